// Round 11
// baseline (712.213 us; speedup 1.0000x reference)
//
#include <hip/hip_runtime.h>

#define NF 128
#define NBSHIFT 8        // 256 nodes per bucket
#define NBMAX 512        // padded bucket count for scans
#define CHUNK 4096       // edges per multisplit chunk

typedef __attribute__((ext_vector_type(8))) short bf16x8;
typedef __attribute__((ext_vector_type(4))) float f32x4;
typedef __attribute__((ext_vector_type(2))) float f32x2;

__device__ __forceinline__ unsigned short f2bf(float f) {
    unsigned int u = __builtin_bit_cast(unsigned int, f);
    u = (u + 0x7fffu + ((u >> 16) & 1u)) >> 16;
    return (unsigned short)u;
}
__device__ __forceinline__ float bflo(unsigned int u) {
    return __builtin_bit_cast(float, u << 16);
}
__device__ __forceinline__ float bfhi(unsigned int u) {
    return __builtin_bit_cast(float, u & 0xffff0000u);
}
__device__ __forceinline__ unsigned char f2fp8(float v) {
    return (unsigned char)(__builtin_amdgcn_cvt_pk_fp8_f32(v, v, 0, false) & 0xff);
}

// ================= fused prep: bhist | buildBt | cvt(x -> bf16 + fp8) =================
#define BH 256
#define BT 256
__global__ __launch_bounds__(256) void k_prep(const int* __restrict__ dst, int E, int NB,
                                              int* __restrict__ gbhist,
                                              const float* __restrict__ x,
                                              unsigned short* __restrict__ xb,
                                              unsigned char* __restrict__ xq,
                                              const float* __restrict__ Win,
                                              const float* __restrict__ Wout,
                                              unsigned short* __restrict__ BtIn,
                                              unsigned short* __restrict__ BtOut) {
    __shared__ int lh[NBMAX];
    const int bb = blockIdx.x;
    const int t = threadIdx.x;
    if (bb < BH) {
        for (int k = t; k < NBMAX; k += 256) lh[k] = 0;
        __syncthreads();
        for (int i = bb * 256 + t; i < E; i += BH * 256)
            atomicAdd(&lh[((unsigned)dst[i]) >> NBSHIFT], 1);
        __syncthreads();
        for (int k = t; k < NB; k += 256)
            if (lh[k]) atomicAdd(&gbhist[k], lh[k]);
    } else if (bb < BH + BT) {
        int b2 = bb - BH;
        const float* W = (b2 < 128) ? Win : Wout;
        unsigned short* Bt = (b2 < 128) ? BtIn : BtOut;
        int idx = (b2 & 127) * 256 + t;
        int c = idx >> 8;
        int k = idx & 255;
        int p = k >> 7, kk = k & 127;
        Bt[idx] = f2bf(W[((size_t)p * NF + kk) * NF + c]);
    } else {
        long long i = (long long)(bb - BH - BT) * 256 + t;
        const float4 a = *reinterpret_cast<const float4*>(x + i * 8);
        const float4 b = *reinterpret_cast<const float4*>(x + i * 8 + 4);
        union { unsigned short s[8]; uint4 u; } o;
        o.s[0] = f2bf(a.x); o.s[1] = f2bf(a.y); o.s[2] = f2bf(a.z); o.s[3] = f2bf(a.w);
        o.s[4] = f2bf(b.x); o.s[5] = f2bf(b.y); o.s[6] = f2bf(b.z); o.s[7] = f2bf(b.w);
        *reinterpret_cast<uint4*>(xb + i * 8) = o.u;
        int lo = __builtin_amdgcn_cvt_pk_fp8_f32(a.x, a.y, 0, false);
        lo = __builtin_amdgcn_cvt_pk_fp8_f32(a.z, a.w, lo, true);
        int hi = __builtin_amdgcn_cvt_pk_fp8_f32(b.x, b.y, 0, false);
        hi = __builtin_amdgcn_cvt_pk_fp8_f32(b.z, b.w, hi, true);
        uint2 oq; oq.x = (unsigned)lo; oq.y = (unsigned)hi;
        *reinterpret_cast<uint2*>(xq + i * 8) = oq;
    }
}

// ================= CSR build =================

__global__ __launch_bounds__(256) void k_bscan(const int* __restrict__ gbhist,
                                               int* __restrict__ bbase, int* __restrict__ gcursor,
                                               int NB, int E, int* __restrict__ offsets, int n) {
    __shared__ int sA[NBMAX], sB[NBMAX];
    int t = threadIdx.x;
    for (int k = t; k < NBMAX; k += 256) sA[k] = (k < NB) ? gbhist[k] : 0;
    __syncthreads();
    int* pin = sA;
    int* pout = sB;
    for (int off = 1; off < NBMAX; off <<= 1) {
        for (int k = t; k < NBMAX; k += 256) pout[k] = pin[k] + (k >= off ? pin[k - off] : 0);
        __syncthreads();
        int* tmp = pin; pin = pout; pout = tmp;
    }
    for (int k = t; k < NB; k += 256) {
        int excl = pin[k] - gbhist[k];
        bbase[k] = excl;
        gcursor[k] = excl;
    }
    if (t == 0) {
        bbase[NB] = E;
        offsets[n] = E;
    }
}

// chunked multisplit; edge packed 32-bit: (dst&255)<<24 | src  (needs n < 2^24)
__global__ __launch_bounds__(256) void k_bucket(const int* __restrict__ src,
                                                const int* __restrict__ dst,
                                                int* __restrict__ gcursor,
                                                unsigned* __restrict__ gpairs, int E) {
    __shared__ int lhist[NBMAX], lbase[NBMAX], lcur[NBMAX], gb[NBMAX];
    __shared__ int sA[NBMAX], sB[NBMAX];
    __shared__ unsigned stage[CHUNK];
    __shared__ unsigned short stage_b[CHUNK];
    const int t = threadIdx.x;
    const int c0 = blockIdx.x * CHUNK;
    const int cc = min(CHUNK, E - c0);

    for (int k = t; k < NBMAX; k += 256) lhist[k] = 0;
    __syncthreads();

    int ls[16], ld[16];
#pragma unroll
    for (int j = 0; j < 16; ++j) {
        int i = t + j * 256;
        ls[j] = 0; ld[j] = 0;
        if (i < cc) {
            ls[j] = src[c0 + i];
            ld[j] = dst[c0 + i];
            atomicAdd(&lhist[((unsigned)ld[j]) >> NBSHIFT], 1);
        }
    }
    __syncthreads();
    for (int k = t; k < NBMAX; k += 256) sA[k] = lhist[k];
    __syncthreads();
    int* pin = sA;
    int* pout = sB;
    for (int off = 1; off < NBMAX; off <<= 1) {
        for (int k = t; k < NBMAX; k += 256) pout[k] = pin[k] + (k >= off ? pin[k - off] : 0);
        __syncthreads();
        int* tmp = pin; pin = pout; pout = tmp;
    }
    for (int k = t; k < NBMAX; k += 256) {
        int excl = pin[k] - lhist[k];
        lbase[k] = excl;
        lcur[k] = excl;
        int cnt = lhist[k];
        if (cnt > 0) gb[k] = atomicAdd(&gcursor[k], cnt);
    }
    __syncthreads();
#pragma unroll
    for (int j = 0; j < 16; ++j) {
        int i = t + j * 256;
        if (i < cc) {
            int b = ((unsigned)ld[j]) >> NBSHIFT;
            int pos = atomicAdd(&lcur[b], 1);
            stage[pos] = (((unsigned)ld[j] & 255u) << 24) | (unsigned)ls[j];
            stage_b[pos] = (unsigned short)b;
        }
    }
    __syncthreads();
    for (int idx = t; idx < cc; idx += 256) {
        unsigned p = stage[idx];
        int b = stage_b[idx];
        gpairs[gb[b] + (idx - lbase[b])] = p;
    }
}

// per-bucket: per-node hist + scan -> offsets/invdeg/degb (+global degree hist),
// scatter esrc within bucket region
__global__ __launch_bounds__(256) void k_bsort(const unsigned* __restrict__ gpairs,
                                               const int* __restrict__ bbase,
                                               int* __restrict__ offsets,
                                               float* __restrict__ invdeg,
                                               unsigned char* __restrict__ degb,
                                               int* __restrict__ gdhist,
                                               int* __restrict__ esrc, int n) {
    __shared__ int lcnt[256], lcur[256], sA[256], sB[256];
    const int b = blockIdx.x;
    const int t = threadIdx.x;
    const int base = bbase[b];
    const int c = bbase[b + 1] - base;
    const int n0 = b << NBSHIFT;

    lcnt[t] = 0;
    __syncthreads();
    for (int i = t; i < c; i += 256) {
        int node = (int)(gpairs[base + i] >> 24);
        atomicAdd(&lcnt[node], 1);
    }
    __syncthreads();
    sA[t] = lcnt[t];
    __syncthreads();
    int* pin = sA;
    int* pout = sB;
    for (int off = 1; off < 256; off <<= 1) {
        pout[t] = pin[t] + (t >= off ? pin[t - off] : 0);
        __syncthreads();
        int* tmp = pin; pin = pout; pout = tmp;
    }
    int excl = pin[t] - lcnt[t];
    lcur[t] = excl;
    int node_g = n0 + t;
    if (node_g < n) {
        offsets[node_g] = base + excl;
        invdeg[node_g] = 1.0f / (float)max(lcnt[t], 1);
        int d = min(lcnt[t], 255);
        degb[node_g] = (unsigned char)d;
        atomicAdd(&gdhist[d], 1);
    }
    __syncthreads();
    for (int i = t; i < c; i += 256) {
        unsigned p = gpairs[base + i];
        int node = (int)(p >> 24);
        int pos = atomicAdd(&lcur[node], 1);
        esrc[base + pos] = (int)(p & 0x00ffffffu);
    }
}

// degree counting-sort: scan 256-bin hist -> cursors
__global__ void k_dscan(const int* __restrict__ gdhist, int* __restrict__ dcur) {
    __shared__ int sh[256];
    int t = threadIdx.x;
    int v = gdhist[t];
    sh[t] = v;
    __syncthreads();
    for (int off = 1; off < 256; off <<= 1) {
        int x = (t >= off) ? sh[t - off] : 0;
        __syncthreads();
        sh[t] += x;
        __syncthreads();
    }
    dcur[t] = sh[t] - v;  // exclusive base
}

__global__ void k_dfill(const unsigned char* __restrict__ degb, int* __restrict__ dcur,
                        int* __restrict__ dorder, int n) {
    int i = blockIdx.x * blockDim.x + threadIdx.x;
    int stride = gridDim.x * blockDim.x;
    for (; i < n; i += stride) {
        int d = degb[i];
        int pos = atomicAdd(&dcur[d], 1);
        dorder[pos] = i;
    }
}

// ================= gather aggregation: 4 nodes per wave, fp8 source ==============
// lane = (g = lane>>4: node slot, q = lane&15: 8-col group). Nodes taken in
// degree-sorted order (dorder) so the 4 groups run near-lockstep; no cross-lane
// reduction -- each 16-lane group's partials ARE its node's output columns.
__global__ __launch_bounds__(256) void k_agg4(const unsigned char* __restrict__ feat,
                                              const int* __restrict__ esrc,
                                              const int* __restrict__ offsets,
                                              const float* __restrict__ invdeg,
                                              const int* __restrict__ dorder,
                                              unsigned short* __restrict__ neigh, int n) {
    const int tid = threadIdx.x;
    const int wv = (int)(((long long)blockIdx.x * blockDim.x + tid) >> 6);
    if (wv * 4 >= n) return;
    const int lane = tid & 63;
    const int g = lane >> 4;
    const int q = lane & 15;
    const int i4 = wv * 4 + g;

    int node = 0, beg = 0, deg = 0;
    if (i4 < n) {
        node = dorder[i4];
        beg = offsets[node];
        deg = offsets[node + 1] - beg;
    }
    int mn = deg, mx = deg;
    int s1 = __shfl_xor(mn, 16); mn = min(mn, s1);
    int s2 = __shfl_xor(mx, 16); mx = max(mx, s2);
    s1 = __shfl_xor(mn, 32); mn = min(mn, s1);
    s2 = __shfl_xor(mx, 32); mx = max(mx, s2);
    const int mindeg = __builtin_amdgcn_readfirstlane(mn);
    const int maxdeg = __builtin_amdgcn_readfirstlane(mx);

    const unsigned qoff = (unsigned)q * 8u;
    f32x2 c01 = {0.f, 0.f}, c23 = {0.f, 0.f}, c45 = {0.f, 0.f}, c67 = {0.f, 0.f};

    int i = 0;
    for (; i + 4 <= mindeg; i += 4) {
        int e0 = esrc[beg + i + 0];
        int e1 = esrc[beg + i + 1];
        int e2 = esrc[beg + i + 2];
        int e3 = esrc[beg + i + 3];
        uint2 v0 = *(const uint2*)(feat + (unsigned)e0 * 128u + qoff);
        uint2 v1 = *(const uint2*)(feat + (unsigned)e1 * 128u + qoff);
        uint2 v2 = *(const uint2*)(feat + (unsigned)e2 * 128u + qoff);
        uint2 v3 = *(const uint2*)(feat + (unsigned)e3 * 128u + qoff);
        c01 += __builtin_amdgcn_cvt_pk_f32_fp8((int)v0.x, false);
        c23 += __builtin_amdgcn_cvt_pk_f32_fp8((int)v0.x, true);
        c45 += __builtin_amdgcn_cvt_pk_f32_fp8((int)v0.y, false);
        c67 += __builtin_amdgcn_cvt_pk_f32_fp8((int)v0.y, true);
        c01 += __builtin_amdgcn_cvt_pk_f32_fp8((int)v1.x, false);
        c23 += __builtin_amdgcn_cvt_pk_f32_fp8((int)v1.x, true);
        c45 += __builtin_amdgcn_cvt_pk_f32_fp8((int)v1.y, false);
        c67 += __builtin_amdgcn_cvt_pk_f32_fp8((int)v1.y, true);
        c01 += __builtin_amdgcn_cvt_pk_f32_fp8((int)v2.x, false);
        c23 += __builtin_amdgcn_cvt_pk_f32_fp8((int)v2.x, true);
        c45 += __builtin_amdgcn_cvt_pk_f32_fp8((int)v2.y, false);
        c67 += __builtin_amdgcn_cvt_pk_f32_fp8((int)v2.y, true);
        c01 += __builtin_amdgcn_cvt_pk_f32_fp8((int)v3.x, false);
        c23 += __builtin_amdgcn_cvt_pk_f32_fp8((int)v3.x, true);
        c45 += __builtin_amdgcn_cvt_pk_f32_fp8((int)v3.y, false);
        c67 += __builtin_amdgcn_cvt_pk_f32_fp8((int)v3.y, true);
    }
    // remainder (degree-sorted batches keep this short)
    for (; i < maxdeg; ++i) {
        if (i < deg) {
            int e = esrc[beg + i];
            uint2 v = *(const uint2*)(feat + (unsigned)e * 128u + qoff);
            c01 += __builtin_amdgcn_cvt_pk_f32_fp8((int)v.x, false);
            c23 += __builtin_amdgcn_cvt_pk_f32_fp8((int)v.x, true);
            c45 += __builtin_amdgcn_cvt_pk_f32_fp8((int)v.y, false);
            c67 += __builtin_amdgcn_cvt_pk_f32_fp8((int)v.y, true);
        }
    }

    if (i4 < n) {
        const float sc = invdeg[node];
        float a0 = c01.x * sc, a1 = c01.y * sc, a2 = c23.x * sc, a3 = c23.y * sc;
        float a4 = c45.x * sc, a5 = c45.y * sc, a6 = c67.x * sc, a7 = c67.y * sc;
        unsigned p0, p1, p2, p3;
        asm("v_cvt_pk_bf16_f32 %0, %1, %2" : "=v"(p0) : "v"(a0), "v"(a1));
        asm("v_cvt_pk_bf16_f32 %0, %1, %2" : "=v"(p1) : "v"(a2), "v"(a3));
        asm("v_cvt_pk_bf16_f32 %0, %1, %2" : "=v"(p2) : "v"(a4), "v"(a5));
        asm("v_cvt_pk_bf16_f32 %0, %1, %2" : "=v"(p3) : "v"(a6), "v"(a7));
        uint4 o; o.x = p0; o.y = p1; o.z = p2; o.w = p3;
        *(uint4*)((char*)neigh + (size_t)node * 256 + (unsigned)q * 16u) = o;
    }
}

// fallback bf16-source aggregate (non-fp8 path)
__global__ __launch_bounds__(256) void k_agg_bf16(const unsigned short* __restrict__ feat,
                                                  const int* __restrict__ esrc,
                                                  const int* __restrict__ offsets,
                                                  const float* __restrict__ invdeg,
                                                  unsigned short* __restrict__ neigh, int n) {
    int wid0 = (int)(((long long)blockIdx.x * blockDim.x + threadIdx.x) >> 6);
    const int wid = __builtin_amdgcn_readfirstlane(wid0);
    if (wid >= n) return;
    const int lane = threadIdx.x & 63;
    const int g = lane >> 4;
    const int q = lane & 15;
    const unsigned qoff = (unsigned)q * 16u;
    const char* fb = (const char*)feat;
    const int beg = offsets[wid];
    const int end = offsets[wid + 1];
    float a0 = 0.f, a1 = 0.f, a2 = 0.f, a3 = 0.f, a4 = 0.f, a5 = 0.f, a6 = 0.f, a7 = 0.f;
    int i = beg;
    for (; i + 4 <= end; i += 4) {
        int e0 = esrc[i + 0], e1 = esrc[i + 1], e2 = esrc[i + 2], e3 = esrc[i + 3];
        int es = (g & 2) ? ((g & 1) ? e3 : e2) : ((g & 1) ? e1 : e0);
        uint4 v = *(const uint4*)(fb + (unsigned)es * 256u + qoff);
        a0 += bflo(v.x); a1 += bfhi(v.x);
        a2 += bflo(v.y); a3 += bfhi(v.y);
        a4 += bflo(v.z); a5 += bfhi(v.z);
        a6 += bflo(v.w); a7 += bfhi(v.w);
    }
    if (i < end) {
        int r = end - i;
        if (g < r) {
            int es = esrc[i + g];
            uint4 v = *(const uint4*)(fb + (unsigned)es * 256u + qoff);
            a0 += bflo(v.x); a1 += bfhi(v.x);
            a2 += bflo(v.y); a3 += bfhi(v.y);
            a4 += bflo(v.z); a5 += bfhi(v.z);
            a6 += bflo(v.w); a7 += bfhi(v.w);
        }
    }
    a0 += __shfl_xor(a0, 16); a1 += __shfl_xor(a1, 16);
    a2 += __shfl_xor(a2, 16); a3 += __shfl_xor(a3, 16);
    a4 += __shfl_xor(a4, 16); a5 += __shfl_xor(a5, 16);
    a6 += __shfl_xor(a6, 16); a7 += __shfl_xor(a7, 16);
    a0 += __shfl_xor(a0, 32); a1 += __shfl_xor(a1, 32);
    a2 += __shfl_xor(a2, 32); a3 += __shfl_xor(a3, 32);
    a4 += __shfl_xor(a4, 32); a5 += __shfl_xor(a5, 32);
    a6 += __shfl_xor(a6, 32); a7 += __shfl_xor(a7, 32);
    const float sc = invdeg[wid];
    a0 *= sc; a1 *= sc; a2 *= sc; a3 *= sc;
    a4 *= sc; a5 *= sc; a6 *= sc; a7 *= sc;
    unsigned p0, p1, p2, p3;
    asm("v_cvt_pk_bf16_f32 %0, %1, %2" : "=v"(p0) : "v"(a0), "v"(a1));
    asm("v_cvt_pk_bf16_f32 %0, %1, %2" : "=v"(p1) : "v"(a2), "v"(a3));
    asm("v_cvt_pk_bf16_f32 %0, %1, %2" : "=v"(p2) : "v"(a4), "v"(a5));
    asm("v_cvt_pk_bf16_f32 %0, %1, %2" : "=v"(p3) : "v"(a6), "v"(a7));
    if (g == 0) {
        uint4 o; o.x = p0; o.y = p1; o.z = p2; o.w = p3;
        *(uint4*)((char*)neigh + (size_t)wid * 256 + qoff) = o;
    }
}

// fallback fp32-source aggregate
__global__ __launch_bounds__(256) void k_agg_f32(const float* __restrict__ feat,
                                                 const int* __restrict__ esrc,
                                                 const int* __restrict__ offsets,
                                                 const float* __restrict__ invdeg,
                                                 unsigned short* __restrict__ neigh, int n) {
    int wid0 = (int)(((long long)blockIdx.x * blockDim.x + threadIdx.x) >> 6);
    const int wid = __builtin_amdgcn_readfirstlane(wid0);
    if (wid >= n) return;
    int lane = threadIdx.x & 63;
    int beg = offsets[wid], end = offsets[wid + 1];
    float a0 = 0.f, a1 = 0.f;
    for (int i = beg; i < end; ++i) {
        int s0 = esrc[i];
        float2 v0 = *(const float2*)(feat + (size_t)s0 * NF + lane * 2);
        a0 += v0.x; a1 += v0.y;
    }
    float sc = invdeg[wid];
    unsigned pk;
    float ca = a0 * sc, cb = a1 * sc;
    asm("v_cvt_pk_bf16_f32 %0, %1, %2" : "=v"(pk) : "v"(ca), "v"(cb));
    *(unsigned*)(neigh + (size_t)wid * NF + lane * 2) = pk;
}

// ================= MFMA GEMM, LDS-staged (fp8 path) =================
template <bool RELU, bool OUTBF16, bool WRITEQ>
__global__ __launch_bounds__(256) void k_gemm_lds(const unsigned short* __restrict__ A1,
                                                  const unsigned short* __restrict__ A2,
                                                  const unsigned short* __restrict__ Bt,
                                                  void* __restrict__ outv,
                                                  unsigned char* __restrict__ outq,
                                                  int nrows) {
    __shared__ __align__(16) unsigned char sm[32768];  // [2][64 rows][128 k] bf16
    const int tid = threadIdx.x;
    const int w = tid >> 6;
    const int lane = tid & 63;
    const int l15 = lane & 15;
    const int lk = lane >> 4;  // 0..3
    const int col0 = w * 32;
    const int rbase = blockIdx.x * 64;

#pragma unroll
    for (int h = 0; h < 2; ++h) {
        const unsigned short* Ah = h ? A2 : A1;
#pragma unroll
        for (int j = 0; j < 4; ++j) {
            const int r = w * 16 + j * 4 + lk;
            const int garow = min(rbase + r, nrows - 1);
            const int cch = l15 ^ (r & 7);
            const unsigned short* srcp = Ah + (size_t)garow * NF + cch * 8;
            unsigned char* ldst = &sm[h * 16384 + (w * 16 + j * 4) * 256];
            __builtin_amdgcn_global_load_lds(
                (const __attribute__((address_space(1))) void*)srcp,
                (__attribute__((address_space(3))) void*)ldst, 16, 0, 0);
        }
    }

    bf16x8 breg[2][8];
#pragma unroll
    for (int c = 0; c < 2; ++c)
#pragma unroll
        for (int kc = 0; kc < 8; ++kc)
            breg[c][kc] = *(const bf16x8*)(Bt + (size_t)(col0 + c * 16 + l15) * 256 +
                                           kc * 32 + lk * 8);

    f32x4 acc[4][2];
#pragma unroll
    for (int rc = 0; rc < 4; ++rc) {
        acc[rc][0] = (f32x4)0.0f;
        acc[rc][1] = (f32x4)0.0f;
    }

    __syncthreads();

#pragma unroll
    for (int rc = 0; rc < 4; ++rc) {
        const int row = rc * 16 + l15;
#pragma unroll
        for (int kc = 0; kc < 8; ++kc) {
            const int half = kc >> 2;
            const int kk = kc & 3;
            const int chunk = (kk * 4 + lk) ^ (row & 7);
            const bf16x8 a = *(const bf16x8*)&sm[half * 16384 + row * 256 + chunk * 16];
            acc[rc][0] = __builtin_amdgcn_mfma_f32_16x16x32_bf16(a, breg[0][kc],
                                                                 acc[rc][0], 0, 0, 0);
            acc[rc][1] = __builtin_amdgcn_mfma_f32_16x16x32_bf16(a, breg[1][kc],
                                                                 acc[rc][1], 0, 0, 0);
        }
    }

    __syncthreads();

    if (OUTBF16) {
        unsigned short* smb = (unsigned short*)sm;
        unsigned char* smq = sm + 16384;
#pragma unroll
        for (int rc = 0; rc < 4; ++rc)
#pragma unroll
            for (int r = 0; r < 4; ++r) {
                const int row = rc * 16 + lk * 4 + r;
#pragma unroll
                for (int c = 0; c < 2; ++c) {
                    float v = acc[rc][c][r];
                    if (RELU) v = fmaxf(v, 0.f);
                    const int col = col0 + c * 16 + l15;
                    smb[row * NF + col] = f2bf(v);
                    if (WRITEQ) smq[row * NF + col] = f2fp8(v);
                }
            }
        __syncthreads();
#pragma unroll
        for (int it = 0; it < 4; ++it) {
            const int off = (tid + it * 256) * 16;
            if (rbase + (off >> 8) < nrows)
                *(uint4*)((char*)outv + (size_t)rbase * 256 + off) =
                    *(const uint4*)&sm[off];
        }
        if (WRITEQ) {
#pragma unroll
            for (int it = 0; it < 2; ++it) {
                const int off = (tid + it * 256) * 16;
                if (rbase + (off >> 7) < nrows)
                    *(uint4*)(outq + (size_t)rbase * 128 + off) =
                        *(const uint4*)&sm[16384 + off];
            }
        }
    } else {
        float* smf = (float*)sm;
#pragma unroll
        for (int rc = 0; rc < 4; ++rc)
#pragma unroll
            for (int r = 0; r < 4; ++r) {
                const int row = rc * 16 + lk * 4 + r;
#pragma unroll
                for (int c = 0; c < 2; ++c) {
                    float v = acc[rc][c][r];
                    if (RELU) v = fmaxf(v, 0.f);
                    smf[row * NF + col0 + c * 16 + l15] = v;
                }
            }
        __syncthreads();
#pragma unroll
        for (int it = 0; it < 8; ++it) {
            const int off = (tid + it * 256) * 16;
            if (rbase + (off >> 9) < nrows)
                *(uint4*)((char*)outv + (size_t)rbase * 512 + off) =
                    *(const uint4*)&sm[off];
        }
    }
}

// ================= fallback GEMM (non-fp8 path) =================
template <bool RELU, bool A1BF16, bool OUTBF16>
__global__ __launch_bounds__(256) void k_gemm_mfma(const void* __restrict__ A1v,
                                                   const unsigned short* __restrict__ A2,
                                                   const unsigned short* __restrict__ Bt,
                                                   void* __restrict__ outv, int nrows) {
    const int tid = threadIdx.x;
    const int wave = tid >> 6;
    const int lane = tid & 63;
    const int l15 = lane & 15;
    const int lk = lane >> 4;
    const int col0 = wave * 32;
    const int rbase = blockIdx.x * 64;

    bf16x8 breg[2][8];
#pragma unroll
    for (int c = 0; c < 2; ++c)
#pragma unroll
        for (int kc = 0; kc < 8; ++kc)
            breg[c][kc] = *(const bf16x8*)(Bt + (size_t)(col0 + c * 16 + l15) * 256 +
                                           kc * 32 + lk * 8);

    f32x4 acc[4][2];
#pragma unroll
    for (int rc = 0; rc < 4; ++rc) {
        acc[rc][0] = (f32x4)0.0f;
        acc[rc][1] = (f32x4)0.0f;
    }

#pragma unroll
    for (int rc = 0; rc < 4; ++rc) {
        const int arow = rbase + rc * 16 + l15;
        const bool ok = arow < nrows;
        bf16x8 a[8];
        if (ok) {
            if (A1BF16) {
                const unsigned short* A1 = (const unsigned short*)A1v;
#pragma unroll
                for (int kc = 0; kc < 4; ++kc) {
                    a[kc] = *(const bf16x8*)(A1 + (size_t)arow * NF + kc * 32 + lk * 8);
                    a[kc + 4] = *(const bf16x8*)(A2 + (size_t)arow * NF + kc * 32 + lk * 8);
                }
            } else {
                const float* A1 = (const float*)A1v;
#pragma unroll
                for (int kc = 0; kc < 4; ++kc) {
                    const float* p = A1 + (size_t)arow * NF + kc * 32 + lk * 8;
                    float4 u = *(const float4*)p;
                    float4 v = *(const float4*)(p + 4);
                    a[kc][0] = (short)f2bf(u.x); a[kc][1] = (short)f2bf(u.y);
                    a[kc][2] = (short)f2bf(u.z); a[kc][3] = (short)f2bf(u.w);
                    a[kc][4] = (short)f2bf(v.x); a[kc][5] = (short)f2bf(v.y);
                    a[kc][6] = (short)f2bf(v.z); a[kc][7] = (short)f2bf(v.w);
                    a[kc + 4] = *(const bf16x8*)(A2 + (size_t)arow * NF + kc * 32 + lk * 8);
                }
            }
        } else {
#pragma unroll
            for (int kc = 0; kc < 8; ++kc) a[kc] = (bf16x8)(short)0;
        }
#pragma unroll
        for (int kc = 0; kc < 8; ++kc) {
            acc[rc][0] = __builtin_amdgcn_mfma_f32_16x16x32_bf16(a[kc], breg[0][kc],
                                                                 acc[rc][0], 0, 0, 0);
            acc[rc][1] = __builtin_amdgcn_mfma_f32_16x16x32_bf16(a[kc], breg[1][kc],
                                                                 acc[rc][1], 0, 0, 0);
        }
    }

#pragma unroll
    for (int rc = 0; rc < 4; ++rc) {
#pragma unroll
        for (int r = 0; r < 4; ++r) {
            const int orow = rbase + rc * 16 + lk * 4 + r;
            if (orow >= nrows) continue;
#pragma unroll
            for (int c = 0; c < 2; ++c) {
                float v = acc[rc][c][r];
                if (RELU) v = fmaxf(v, 0.f);
                const int col = col0 + c * 16 + l15;
                if (OUTBF16)
                    ((unsigned short*)outv)[(size_t)orow * NF + col] = f2bf(v);
                else
                    ((float*)outv)[(size_t)orow * NF + col] = v;
            }
        }
    }
}

extern "C" void kernel_launch(void* const* d_in, const int* in_sizes, int n_in,
                              void* d_out, int out_size, void* d_ws, size_t ws_size,
                              hipStream_t stream) {
    const float* x = (const float*)d_in[0];
    const float* W_in = (const float*)d_in[1];
    const float* W_out = (const float*)d_in[2];
    const int* src = (const int*)d_in[3];
    const int* dst = (const int*)d_in[4];

    const int n = in_sizes[0] / NF;  // 100000  (must stay < 2^24 for packed CSR)
    const int E = in_sizes[3];       // 1600000
    float* outp = (float*)d_out;

    const int NB = (n + 255) >> NBSHIFT;
    const int nchunks = (E + CHUNK - 1) / CHUNK;

    // workspace carve
    char* ws = (char*)d_ws;
    size_t off = 0;
    auto take = [&](size_t bytes) {
        void* p = ws + off;
        off = (off + bytes + 511) & ~(size_t)511;
        return p;
    };
    int* gbhist = (int*)take((size_t)NB * 4);
    int* bbase = (int*)take((size_t)(NB + 1) * 4);
    int* gcursor = (int*)take((size_t)NB * 4);
    int* offsets = (int*)take((size_t)(n + 1) * 4);
    float* invdeg = (float*)take((size_t)n * 4);
    unsigned short* BtIn = (unsigned short*)take(128 * 256 * 2);
    unsigned short* BtOut = (unsigned short*)take(128 * 256 * 2);
    unsigned* gpairs = (unsigned*)take((size_t)E * 4);
    int* esrc = (int*)take((size_t)E * 4);
    unsigned short* hb = (unsigned short*)take((size_t)n * NF * 2);
    unsigned short* neigh = (unsigned short*)take((size_t)n * NF * 2);
    unsigned char* degb = (unsigned char*)take((size_t)n);
    int* gdhist = (int*)take(256 * 4);
    int* dcur = (int*)take(256 * 4);
    int* dorder = (int*)take((size_t)n * 4);
    size_t need_fp8 = off + (size_t)n * NF * 2 + 512 + (size_t)n * NF + 512 +
                      (size_t)n * NF + 512;
    bool use_fp8 = (ws_size >= need_fp8);
    unsigned short* xb = nullptr;
    unsigned char* xq = nullptr;
    unsigned char* hq = nullptr;
    if (use_fp8) {
        xb = (unsigned short*)take((size_t)n * NF * 2);
        xq = (unsigned char*)take((size_t)n * NF);
        hq = (unsigned char*)take((size_t)n * NF);
    }
    bool use_xb = use_fp8 || (ws_size >= off + (size_t)n * NF * 2);
    if (!use_fp8 && use_xb) xb = (unsigned short*)take((size_t)n * NF * 2);

    // ---- fused prep (bhist | buildBt | x->bf16+fp8) + CSR build ----
    hipMemsetAsync(gbhist, 0, (size_t)NB * 4, stream);
    hipMemsetAsync(gdhist, 0, 256 * 4, stream);
    const int cvtBlocks = use_fp8 ? (int)(((long long)n * NF / 8 + 255) / 256) : 0;
    k_prep<<<BH + BT + cvtBlocks, 256, 0, stream>>>(dst, E, NB, gbhist, x, xb, xq,
                                                    W_in, W_out, BtIn, BtOut);
    k_bscan<<<1, 256, 0, stream>>>(gbhist, bbase, gcursor, NB, E, offsets, n);
    k_bucket<<<nchunks, 256, 0, stream>>>(src, dst, gcursor, gpairs, E);
    k_bsort<<<NB, 256, 0, stream>>>(gpairs, bbase, offsets, invdeg, degb, gdhist, esrc, n);

    const int gemmBlocks = (n + 63) / 64;

    if (use_fp8) {
        // degree counting-sort -> dorder
        k_dscan<<<1, 256, 0, stream>>>(gdhist, dcur);
        k_dfill<<<128, 256, 0, stream>>>(degb, dcur, dorder, n);

        const int agg4Blocks = (n + 15) / 16;  // 16 nodes per 256-thread block
        // ---- layer 0 ----
        k_agg4<<<agg4Blocks, 256, 0, stream>>>(xq, esrc, offsets, invdeg, dorder, neigh, n);
        k_gemm_lds<true, true, true>
            <<<gemmBlocks, 256, 0, stream>>>(xb, neigh, BtIn, hb, hq, n);
        // ---- layer 1 ----
        k_agg4<<<agg4Blocks, 256, 0, stream>>>(hq, esrc, offsets, invdeg, dorder, neigh, n);
        k_gemm_lds<false, false, false>
            <<<gemmBlocks, 256, 0, stream>>>(hb, neigh, BtOut, outp, nullptr, n);
    } else {
        const int aggBlocks = (n + 3) / 4;
        k_agg_f32<<<aggBlocks, 256, 0, stream>>>(x, esrc, offsets, invdeg, neigh, n);
        k_gemm_mfma<true, false, true>
            <<<gemmBlocks, 256, 0, stream>>>(x, neigh, BtIn, hb, n);
        k_agg_bf16<<<aggBlocks, 256, 0, stream>>>(hb, esrc, offsets, invdeg, neigh, n);
        k_gemm_mfma<false, true, false>
            <<<gemmBlocks, 256, 0, stream>>>(hb, neigh, BtOut, outp, n);
    }
}

// Round 12
// 202.184 us; speedup vs baseline: 3.5226x; 3.5226x over previous
//
#include <hip/hip_runtime.h>

#define NF 128
#define NBSHIFT 8        // 256 nodes per bucket
#define NBMAX 512        // padded bucket count for scans
#define CHUNK 4096       // edges per multisplit chunk
#define DCHUNK 4096      // nodes per degree-multisplit chunk

typedef __attribute__((ext_vector_type(8))) short bf16x8;
typedef __attribute__((ext_vector_type(4))) float f32x4;
typedef __attribute__((ext_vector_type(2))) float f32x2;

__device__ __forceinline__ unsigned short f2bf(float f) {
    unsigned int u = __builtin_bit_cast(unsigned int, f);
    u = (u + 0x7fffu + ((u >> 16) & 1u)) >> 16;
    return (unsigned short)u;
}
__device__ __forceinline__ float bflo(unsigned int u) {
    return __builtin_bit_cast(float, u << 16);
}
__device__ __forceinline__ float bfhi(unsigned int u) {
    return __builtin_bit_cast(float, u & 0xffff0000u);
}
__device__ __forceinline__ unsigned char f2fp8(float v) {
    return (unsigned char)(__builtin_amdgcn_cvt_pk_fp8_f32(v, v, 0, false) & 0xff);
}

// ================= fused prep: bhist | buildBt | cvt(x -> bf16 + fp8) =================
#define BH 256
#define BT 256
__global__ __launch_bounds__(256) void k_prep(const int* __restrict__ dst, int E, int NB,
                                              int* __restrict__ gbhist,
                                              const float* __restrict__ x,
                                              unsigned short* __restrict__ xb,
                                              unsigned char* __restrict__ xq,
                                              const float* __restrict__ Win,
                                              const float* __restrict__ Wout,
                                              unsigned short* __restrict__ BtIn,
                                              unsigned short* __restrict__ BtOut) {
    __shared__ int lh[NBMAX];
    const int bb = blockIdx.x;
    const int t = threadIdx.x;
    if (bb < BH) {
        for (int k = t; k < NBMAX; k += 256) lh[k] = 0;
        __syncthreads();
        for (int i = bb * 256 + t; i < E; i += BH * 256)
            atomicAdd(&lh[((unsigned)dst[i]) >> NBSHIFT], 1);
        __syncthreads();
        for (int k = t; k < NB; k += 256)
            if (lh[k]) atomicAdd(&gbhist[k], lh[k]);
    } else if (bb < BH + BT) {
        int b2 = bb - BH;
        const float* W = (b2 < 128) ? Win : Wout;
        unsigned short* Bt = (b2 < 128) ? BtIn : BtOut;
        int idx = (b2 & 127) * 256 + t;
        int c = idx >> 8;
        int k = idx & 255;
        int p = k >> 7, kk = k & 127;
        Bt[idx] = f2bf(W[((size_t)p * NF + kk) * NF + c]);
    } else {
        long long i = (long long)(bb - BH - BT) * 256 + t;
        const float4 a = *reinterpret_cast<const float4*>(x + i * 8);
        const float4 b = *reinterpret_cast<const float4*>(x + i * 8 + 4);
        union { unsigned short s[8]; uint4 u; } o;
        o.s[0] = f2bf(a.x); o.s[1] = f2bf(a.y); o.s[2] = f2bf(a.z); o.s[3] = f2bf(a.w);
        o.s[4] = f2bf(b.x); o.s[5] = f2bf(b.y); o.s[6] = f2bf(b.z); o.s[7] = f2bf(b.w);
        *reinterpret_cast<uint4*>(xb + i * 8) = o.u;
        int lo = __builtin_amdgcn_cvt_pk_fp8_f32(a.x, a.y, 0, false);
        lo = __builtin_amdgcn_cvt_pk_fp8_f32(a.z, a.w, lo, true);
        int hi = __builtin_amdgcn_cvt_pk_fp8_f32(b.x, b.y, 0, false);
        hi = __builtin_amdgcn_cvt_pk_fp8_f32(b.z, b.w, hi, true);
        uint2 oq; oq.x = (unsigned)lo; oq.y = (unsigned)hi;
        *reinterpret_cast<uint2*>(xq + i * 8) = oq;
    }
}

// ================= CSR build =================

__global__ __launch_bounds__(256) void k_bscan(const int* __restrict__ gbhist,
                                               int* __restrict__ bbase, int* __restrict__ gcursor,
                                               int NB, int E, int* __restrict__ offsets, int n) {
    __shared__ int sA[NBMAX], sB[NBMAX];
    int t = threadIdx.x;
    for (int k = t; k < NBMAX; k += 256) sA[k] = (k < NB) ? gbhist[k] : 0;
    __syncthreads();
    int* pin = sA;
    int* pout = sB;
    for (int off = 1; off < NBMAX; off <<= 1) {
        for (int k = t; k < NBMAX; k += 256) pout[k] = pin[k] + (k >= off ? pin[k - off] : 0);
        __syncthreads();
        int* tmp = pin; pin = pout; pout = tmp;
    }
    for (int k = t; k < NB; k += 256) {
        int excl = pin[k] - gbhist[k];
        bbase[k] = excl;
        gcursor[k] = excl;
    }
    if (t == 0) {
        bbase[NB] = E;
        offsets[n] = E;
    }
}

// chunked multisplit; edge packed 32-bit: (dst&255)<<24 | src  (needs n < 2^24)
__global__ __launch_bounds__(256) void k_bucket(const int* __restrict__ src,
                                                const int* __restrict__ dst,
                                                int* __restrict__ gcursor,
                                                unsigned* __restrict__ gpairs, int E) {
    __shared__ int lhist[NBMAX], lbase[NBMAX], lcur[NBMAX], gb[NBMAX];
    __shared__ int sA[NBMAX], sB[NBMAX];
    __shared__ unsigned stage[CHUNK];
    __shared__ unsigned short stage_b[CHUNK];
    const int t = threadIdx.x;
    const int c0 = blockIdx.x * CHUNK;
    const int cc = min(CHUNK, E - c0);

    for (int k = t; k < NBMAX; k += 256) lhist[k] = 0;
    __syncthreads();

    int ls[16], ld[16];
#pragma unroll
    for (int j = 0; j < 16; ++j) {
        int i = t + j * 256;
        ls[j] = 0; ld[j] = 0;
        if (i < cc) {
            ls[j] = src[c0 + i];
            ld[j] = dst[c0 + i];
            atomicAdd(&lhist[((unsigned)ld[j]) >> NBSHIFT], 1);
        }
    }
    __syncthreads();
    for (int k = t; k < NBMAX; k += 256) sA[k] = lhist[k];
    __syncthreads();
    int* pin = sA;
    int* pout = sB;
    for (int off = 1; off < NBMAX; off <<= 1) {
        for (int k = t; k < NBMAX; k += 256) pout[k] = pin[k] + (k >= off ? pin[k - off] : 0);
        __syncthreads();
        int* tmp = pin; pin = pout; pout = tmp;
    }
    for (int k = t; k < NBMAX; k += 256) {
        int excl = pin[k] - lhist[k];
        lbase[k] = excl;
        lcur[k] = excl;
        int cnt = lhist[k];
        if (cnt > 0) gb[k] = atomicAdd(&gcursor[k], cnt);
    }
    __syncthreads();
#pragma unroll
    for (int j = 0; j < 16; ++j) {
        int i = t + j * 256;
        if (i < cc) {
            int b = ((unsigned)ld[j]) >> NBSHIFT;
            int pos = atomicAdd(&lcur[b], 1);
            stage[pos] = (((unsigned)ld[j] & 255u) << 24) | (unsigned)ls[j];
            stage_b[pos] = (unsigned short)b;
        }
    }
    __syncthreads();
    for (int idx = t; idx < cc; idx += 256) {
        unsigned p = stage[idx];
        int b = stage_b[idx];
        gpairs[gb[b] + (idx - lbase[b])] = p;
    }
}

// per-bucket: per-node hist + scan -> offsets/invdeg/degb, LDS-privatized global
// degree histogram (one atomic per nonzero bin per block), scatter esrc in bucket
__global__ __launch_bounds__(256) void k_bsort(const unsigned* __restrict__ gpairs,
                                               const int* __restrict__ bbase,
                                               int* __restrict__ offsets,
                                               float* __restrict__ invdeg,
                                               unsigned char* __restrict__ degb,
                                               int* __restrict__ gdhist,
                                               int* __restrict__ esrc, int n) {
    __shared__ int lcnt[256], lcur[256], sA[256], sB[256], ldh[256];
    const int b = blockIdx.x;
    const int t = threadIdx.x;
    const int base = bbase[b];
    const int c = bbase[b + 1] - base;
    const int n0 = b << NBSHIFT;

    lcnt[t] = 0;
    ldh[t] = 0;
    __syncthreads();
    for (int i = t; i < c; i += 256) {
        int node = (int)(gpairs[base + i] >> 24);
        atomicAdd(&lcnt[node], 1);
    }
    __syncthreads();
    sA[t] = lcnt[t];
    __syncthreads();
    int* pin = sA;
    int* pout = sB;
    for (int off = 1; off < 256; off <<= 1) {
        pout[t] = pin[t] + (t >= off ? pin[t - off] : 0);
        __syncthreads();
        int* tmp = pin; pin = pout; pout = tmp;
    }
    int excl = pin[t] - lcnt[t];
    lcur[t] = excl;
    int node_g = n0 + t;
    if (node_g < n) {
        offsets[node_g] = base + excl;
        invdeg[node_g] = 1.0f / (float)max(lcnt[t], 1);
        int d = min(lcnt[t], 255);
        degb[node_g] = (unsigned char)d;
        atomicAdd(&ldh[d], 1);   // LDS-privatized degree histogram
    }
    __syncthreads();
    if (ldh[t] > 0) atomicAdd(&gdhist[t], ldh[t]);  // <=256 global atomics/block
    for (int i = t; i < c; i += 256) {
        unsigned p = gpairs[base + i];
        int node = (int)(p >> 24);
        int pos = atomicAdd(&lcur[node], 1);
        esrc[base + pos] = (int)(p & 0x00ffffffu);
    }
}

// degree counting-sort pass 1: scan 256-bin hist -> global cursors (exclusive bases)
__global__ void k_dscan(const int* __restrict__ gdhist, int* __restrict__ dcur) {
    __shared__ int sh[256];
    int t = threadIdx.x;
    int v = gdhist[t];
    sh[t] = v;
    __syncthreads();
    for (int off = 1; off < 256; off <<= 1) {
        int x = (t >= off) ? sh[t - off] : 0;
        __syncthreads();
        sh[t] += x;
        __syncthreads();
    }
    dcur[t] = sh[t] - v;  // exclusive base
}

// degree counting-sort pass 2: chunked multisplit (one cursor atomic per bin per block)
__global__ __launch_bounds__(256) void k_dorder(const unsigned char* __restrict__ degb,
                                                int* __restrict__ dcur,
                                                int* __restrict__ dorder, int n) {
    __shared__ int lhist[256], lbase[256], lcur[256], gb[256], sA[256], sB[256];
    __shared__ int stageN[DCHUNK];
    __shared__ unsigned char stageD[DCHUNK];
    const int t = threadIdx.x;
    const int c0 = blockIdx.x * DCHUNK;
    const int cc = min(DCHUNK, n - c0);

    lhist[t] = 0;
    __syncthreads();
    int dloc[16];
#pragma unroll
    for (int j = 0; j < 16; ++j) {
        int i = t + j * 256;
        dloc[j] = -1;
        if (i < cc) {
            dloc[j] = degb[c0 + i];
            atomicAdd(&lhist[dloc[j]], 1);
        }
    }
    __syncthreads();
    sA[t] = lhist[t];
    __syncthreads();
    int* pin = sA;
    int* pout = sB;
    for (int off = 1; off < 256; off <<= 1) {
        pout[t] = pin[t] + (t >= off ? pin[t - off] : 0);
        __syncthreads();
        int* tmp = pin; pin = pout; pout = tmp;
    }
    int excl = pin[t] - lhist[t];
    lbase[t] = excl;
    lcur[t] = excl;
    if (lhist[t] > 0) gb[t] = atomicAdd(&dcur[t], lhist[t]);
    __syncthreads();
#pragma unroll
    for (int j = 0; j < 16; ++j) {
        int i = t + j * 256;
        if (i < cc) {
            int d = dloc[j];
            int pos = atomicAdd(&lcur[d], 1);
            stageN[pos] = c0 + i;
            stageD[pos] = (unsigned char)d;
        }
    }
    __syncthreads();
    for (int idx = t; idx < cc; idx += 256) {
        int d = stageD[idx];
        dorder[gb[d] + (idx - lbase[d])] = stageN[idx];
    }
}

// ================= gather aggregation: 4 nodes per wave, fp8 source ==============
// lane = (g = lane>>4: node slot, q = lane&15: 8-col group). Nodes taken in
// degree-sorted order (dorder) so the 4 groups run near-lockstep; no cross-lane
// reduction -- each 16-lane group's partials ARE its node's output columns.
__global__ __launch_bounds__(256) void k_agg4(const unsigned char* __restrict__ feat,
                                              const int* __restrict__ esrc,
                                              const int* __restrict__ offsets,
                                              const float* __restrict__ invdeg,
                                              const int* __restrict__ dorder,
                                              unsigned short* __restrict__ neigh, int n) {
    const int tid = threadIdx.x;
    const int wv = (int)(((long long)blockIdx.x * blockDim.x + tid) >> 6);
    if (wv * 4 >= n) return;
    const int lane = tid & 63;
    const int g = lane >> 4;
    const int q = lane & 15;
    const int i4 = wv * 4 + g;

    int node = 0, beg = 0, deg = 0;
    if (i4 < n) {
        node = dorder[i4];
        beg = offsets[node];
        deg = offsets[node + 1] - beg;
    }
    int mn = deg, mx = deg;
    int s1 = __shfl_xor(mn, 16); mn = min(mn, s1);
    int s2 = __shfl_xor(mx, 16); mx = max(mx, s2);
    s1 = __shfl_xor(mn, 32); mn = min(mn, s1);
    s2 = __shfl_xor(mx, 32); mx = max(mx, s2);
    const int mindeg = __builtin_amdgcn_readfirstlane(mn);
    const int maxdeg = __builtin_amdgcn_readfirstlane(mx);

    const unsigned qoff = (unsigned)q * 8u;
    f32x2 c01 = {0.f, 0.f}, c23 = {0.f, 0.f}, c45 = {0.f, 0.f}, c67 = {0.f, 0.f};

    int i = 0;
    for (; i + 4 <= mindeg; i += 4) {
        int e0 = esrc[beg + i + 0];
        int e1 = esrc[beg + i + 1];
        int e2 = esrc[beg + i + 2];
        int e3 = esrc[beg + i + 3];
        uint2 v0 = *(const uint2*)(feat + (unsigned)e0 * 128u + qoff);
        uint2 v1 = *(const uint2*)(feat + (unsigned)e1 * 128u + qoff);
        uint2 v2 = *(const uint2*)(feat + (unsigned)e2 * 128u + qoff);
        uint2 v3 = *(const uint2*)(feat + (unsigned)e3 * 128u + qoff);
        c01 += __builtin_amdgcn_cvt_pk_f32_fp8((int)v0.x, false);
        c23 += __builtin_amdgcn_cvt_pk_f32_fp8((int)v0.x, true);
        c45 += __builtin_amdgcn_cvt_pk_f32_fp8((int)v0.y, false);
        c67 += __builtin_amdgcn_cvt_pk_f32_fp8((int)v0.y, true);
        c01 += __builtin_amdgcn_cvt_pk_f32_fp8((int)v1.x, false);
        c23 += __builtin_amdgcn_cvt_pk_f32_fp8((int)v1.x, true);
        c45 += __builtin_amdgcn_cvt_pk_f32_fp8((int)v1.y, false);
        c67 += __builtin_amdgcn_cvt_pk_f32_fp8((int)v1.y, true);
        c01 += __builtin_amdgcn_cvt_pk_f32_fp8((int)v2.x, false);
        c23 += __builtin_amdgcn_cvt_pk_f32_fp8((int)v2.x, true);
        c45 += __builtin_amdgcn_cvt_pk_f32_fp8((int)v2.y, false);
        c67 += __builtin_amdgcn_cvt_pk_f32_fp8((int)v2.y, true);
        c01 += __builtin_amdgcn_cvt_pk_f32_fp8((int)v3.x, false);
        c23 += __builtin_amdgcn_cvt_pk_f32_fp8((int)v3.x, true);
        c45 += __builtin_amdgcn_cvt_pk_f32_fp8((int)v3.y, false);
        c67 += __builtin_amdgcn_cvt_pk_f32_fp8((int)v3.y, true);
    }
    for (; i < maxdeg; ++i) {
        if (i < deg) {
            int e = esrc[beg + i];
            uint2 v = *(const uint2*)(feat + (unsigned)e * 128u + qoff);
            c01 += __builtin_amdgcn_cvt_pk_f32_fp8((int)v.x, false);
            c23 += __builtin_amdgcn_cvt_pk_f32_fp8((int)v.x, true);
            c45 += __builtin_amdgcn_cvt_pk_f32_fp8((int)v.y, false);
            c67 += __builtin_amdgcn_cvt_pk_f32_fp8((int)v.y, true);
        }
    }

    if (i4 < n) {
        const float sc = invdeg[node];
        float a0 = c01.x * sc, a1 = c01.y * sc, a2 = c23.x * sc, a3 = c23.y * sc;
        float a4 = c45.x * sc, a5 = c45.y * sc, a6 = c67.x * sc, a7 = c67.y * sc;
        unsigned p0, p1, p2, p3;
        asm("v_cvt_pk_bf16_f32 %0, %1, %2" : "=v"(p0) : "v"(a0), "v"(a1));
        asm("v_cvt_pk_bf16_f32 %0, %1, %2" : "=v"(p1) : "v"(a2), "v"(a3));
        asm("v_cvt_pk_bf16_f32 %0, %1, %2" : "=v"(p2) : "v"(a4), "v"(a5));
        asm("v_cvt_pk_bf16_f32 %0, %1, %2" : "=v"(p3) : "v"(a6), "v"(a7));
        uint4 o; o.x = p0; o.y = p1; o.z = p2; o.w = p3;
        *(uint4*)((char*)neigh + (size_t)node * 256 + (unsigned)q * 16u) = o;
    }
}

// fallback bf16-source aggregate (non-fp8 path)
__global__ __launch_bounds__(256) void k_agg_bf16(const unsigned short* __restrict__ feat,
                                                  const int* __restrict__ esrc,
                                                  const int* __restrict__ offsets,
                                                  const float* __restrict__ invdeg,
                                                  unsigned short* __restrict__ neigh, int n) {
    int wid0 = (int)(((long long)blockIdx.x * blockDim.x + threadIdx.x) >> 6);
    const int wid = __builtin_amdgcn_readfirstlane(wid0);
    if (wid >= n) return;
    const int lane = threadIdx.x & 63;
    const int g = lane >> 4;
    const int q = lane & 15;
    const unsigned qoff = (unsigned)q * 16u;
    const char* fb = (const char*)feat;
    const int beg = offsets[wid];
    const int end = offsets[wid + 1];
    float a0 = 0.f, a1 = 0.f, a2 = 0.f, a3 = 0.f, a4 = 0.f, a5 = 0.f, a6 = 0.f, a7 = 0.f;
    int i = beg;
    for (; i + 4 <= end; i += 4) {
        int e0 = esrc[i + 0], e1 = esrc[i + 1], e2 = esrc[i + 2], e3 = esrc[i + 3];
        int es = (g & 2) ? ((g & 1) ? e3 : e2) : ((g & 1) ? e1 : e0);
        uint4 v = *(const uint4*)(fb + (unsigned)es * 256u + qoff);
        a0 += bflo(v.x); a1 += bfhi(v.x);
        a2 += bflo(v.y); a3 += bfhi(v.y);
        a4 += bflo(v.z); a5 += bfhi(v.z);
        a6 += bflo(v.w); a7 += bfhi(v.w);
    }
    if (i < end) {
        int r = end - i;
        if (g < r) {
            int es = esrc[i + g];
            uint4 v = *(const uint4*)(fb + (unsigned)es * 256u + qoff);
            a0 += bflo(v.x); a1 += bfhi(v.x);
            a2 += bflo(v.y); a3 += bfhi(v.y);
            a4 += bflo(v.z); a5 += bfhi(v.z);
            a6 += bflo(v.w); a7 += bfhi(v.w);
        }
    }
    a0 += __shfl_xor(a0, 16); a1 += __shfl_xor(a1, 16);
    a2 += __shfl_xor(a2, 16); a3 += __shfl_xor(a3, 16);
    a4 += __shfl_xor(a4, 16); a5 += __shfl_xor(a5, 16);
    a6 += __shfl_xor(a6, 16); a7 += __shfl_xor(a7, 16);
    a0 += __shfl_xor(a0, 32); a1 += __shfl_xor(a1, 32);
    a2 += __shfl_xor(a2, 32); a3 += __shfl_xor(a3, 32);
    a4 += __shfl_xor(a4, 32); a5 += __shfl_xor(a5, 32);
    a6 += __shfl_xor(a6, 32); a7 += __shfl_xor(a7, 32);
    const float sc = invdeg[wid];
    a0 *= sc; a1 *= sc; a2 *= sc; a3 *= sc;
    a4 *= sc; a5 *= sc; a6 *= sc; a7 *= sc;
    unsigned p0, p1, p2, p3;
    asm("v_cvt_pk_bf16_f32 %0, %1, %2" : "=v"(p0) : "v"(a0), "v"(a1));
    asm("v_cvt_pk_bf16_f32 %0, %1, %2" : "=v"(p1) : "v"(a2), "v"(a3));
    asm("v_cvt_pk_bf16_f32 %0, %1, %2" : "=v"(p2) : "v"(a4), "v"(a5));
    asm("v_cvt_pk_bf16_f32 %0, %1, %2" : "=v"(p3) : "v"(a6), "v"(a7));
    if (g == 0) {
        uint4 o; o.x = p0; o.y = p1; o.z = p2; o.w = p3;
        *(uint4*)((char*)neigh + (size_t)wid * 256 + qoff) = o;
    }
}

// fallback fp32-source aggregate
__global__ __launch_bounds__(256) void k_agg_f32(const float* __restrict__ feat,
                                                 const int* __restrict__ esrc,
                                                 const int* __restrict__ offsets,
                                                 const float* __restrict__ invdeg,
                                                 unsigned short* __restrict__ neigh, int n) {
    int wid0 = (int)(((long long)blockIdx.x * blockDim.x + threadIdx.x) >> 6);
    const int wid = __builtin_amdgcn_readfirstlane(wid0);
    if (wid >= n) return;
    int lane = threadIdx.x & 63;
    int beg = offsets[wid], end = offsets[wid + 1];
    float a0 = 0.f, a1 = 0.f;
    for (int i = beg; i < end; ++i) {
        int s0 = esrc[i];
        float2 v0 = *(const float2*)(feat + (size_t)s0 * NF + lane * 2);
        a0 += v0.x; a1 += v0.y;
    }
    float sc = invdeg[wid];
    unsigned pk;
    float ca = a0 * sc, cb = a1 * sc;
    asm("v_cvt_pk_bf16_f32 %0, %1, %2" : "=v"(pk) : "v"(ca), "v"(cb));
    *(unsigned*)(neigh + (size_t)wid * NF + lane * 2) = pk;
}

// ================= MFMA GEMM, LDS-staged (fp8 path) =================
template <bool RELU, bool OUTBF16, bool WRITEQ>
__global__ __launch_bounds__(256) void k_gemm_lds(const unsigned short* __restrict__ A1,
                                                  const unsigned short* __restrict__ A2,
                                                  const unsigned short* __restrict__ Bt,
                                                  void* __restrict__ outv,
                                                  unsigned char* __restrict__ outq,
                                                  int nrows) {
    __shared__ __align__(16) unsigned char sm[32768];  // [2][64 rows][128 k] bf16
    const int tid = threadIdx.x;
    const int w = tid >> 6;
    const int lane = tid & 63;
    const int l15 = lane & 15;
    const int lk = lane >> 4;  // 0..3
    const int col0 = w * 32;
    const int rbase = blockIdx.x * 64;

#pragma unroll
    for (int h = 0; h < 2; ++h) {
        const unsigned short* Ah = h ? A2 : A1;
#pragma unroll
        for (int j = 0; j < 4; ++j) {
            const int r = w * 16 + j * 4 + lk;
            const int garow = min(rbase + r, nrows - 1);
            const int cch = l15 ^ (r & 7);
            const unsigned short* srcp = Ah + (size_t)garow * NF + cch * 8;
            unsigned char* ldst = &sm[h * 16384 + (w * 16 + j * 4) * 256];
            __builtin_amdgcn_global_load_lds(
                (const __attribute__((address_space(1))) void*)srcp,
                (__attribute__((address_space(3))) void*)ldst, 16, 0, 0);
        }
    }

    bf16x8 breg[2][8];
#pragma unroll
    for (int c = 0; c < 2; ++c)
#pragma unroll
        for (int kc = 0; kc < 8; ++kc)
            breg[c][kc] = *(const bf16x8*)(Bt + (size_t)(col0 + c * 16 + l15) * 256 +
                                           kc * 32 + lk * 8);

    f32x4 acc[4][2];
#pragma unroll
    for (int rc = 0; rc < 4; ++rc) {
        acc[rc][0] = (f32x4)0.0f;
        acc[rc][1] = (f32x4)0.0f;
    }

    __syncthreads();

#pragma unroll
    for (int rc = 0; rc < 4; ++rc) {
        const int row = rc * 16 + l15;
#pragma unroll
        for (int kc = 0; kc < 8; ++kc) {
            const int half = kc >> 2;
            const int kk = kc & 3;
            const int chunk = (kk * 4 + lk) ^ (row & 7);
            const bf16x8 a = *(const bf16x8*)&sm[half * 16384 + row * 256 + chunk * 16];
            acc[rc][0] = __builtin_amdgcn_mfma_f32_16x16x32_bf16(a, breg[0][kc],
                                                                 acc[rc][0], 0, 0, 0);
            acc[rc][1] = __builtin_amdgcn_mfma_f32_16x16x32_bf16(a, breg[1][kc],
                                                                 acc[rc][1], 0, 0, 0);
        }
    }

    __syncthreads();

    if (OUTBF16) {
        unsigned short* smb = (unsigned short*)sm;
        unsigned char* smq = sm + 16384;
#pragma unroll
        for (int rc = 0; rc < 4; ++rc)
#pragma unroll
            for (int r = 0; r < 4; ++r) {
                const int row = rc * 16 + lk * 4 + r;
#pragma unroll
                for (int c = 0; c < 2; ++c) {
                    float v = acc[rc][c][r];
                    if (RELU) v = fmaxf(v, 0.f);
                    const int col = col0 + c * 16 + l15;
                    smb[row * NF + col] = f2bf(v);
                    if (WRITEQ) smq[row * NF + col] = f2fp8(v);
                }
            }
        __syncthreads();
#pragma unroll
        for (int it = 0; it < 4; ++it) {
            const int off = (tid + it * 256) * 16;
            if (rbase + (off >> 8) < nrows)
                *(uint4*)((char*)outv + (size_t)rbase * 256 + off) =
                    *(const uint4*)&sm[off];
        }
        if (WRITEQ) {
#pragma unroll
            for (int it = 0; it < 2; ++it) {
                const int off = (tid + it * 256) * 16;
                if (rbase + (off >> 7) < nrows)
                    *(uint4*)(outq + (size_t)rbase * 128 + off) =
                        *(const uint4*)&sm[16384 + off];
            }
        }
    } else {
        float* smf = (float*)sm;
#pragma unroll
        for (int rc = 0; rc < 4; ++rc)
#pragma unroll
            for (int r = 0; r < 4; ++r) {
                const int row = rc * 16 + lk * 4 + r;
#pragma unroll
                for (int c = 0; c < 2; ++c) {
                    float v = acc[rc][c][r];
                    if (RELU) v = fmaxf(v, 0.f);
                    smf[row * NF + col0 + c * 16 + l15] = v;
                }
            }
        __syncthreads();
#pragma unroll
        for (int it = 0; it < 8; ++it) {
            const int off = (tid + it * 256) * 16;
            if (rbase + (off >> 9) < nrows)
                *(uint4*)((char*)outv + (size_t)rbase * 512 + off) =
                    *(const uint4*)&sm[off];
        }
    }
}

// ================= fallback GEMM (non-fp8 path) =================
template <bool RELU, bool A1BF16, bool OUTBF16>
__global__ __launch_bounds__(256) void k_gemm_mfma(const void* __restrict__ A1v,
                                                   const unsigned short* __restrict__ A2,
                                                   const unsigned short* __restrict__ Bt,
                                                   void* __restrict__ outv, int nrows) {
    const int tid = threadIdx.x;
    const int wave = tid >> 6;
    const int lane = tid & 63;
    const int l15 = lane & 15;
    const int lk = lane >> 4;
    const int col0 = wave * 32;
    const int rbase = blockIdx.x * 64;

    bf16x8 breg[2][8];
#pragma unroll
    for (int c = 0; c < 2; ++c)
#pragma unroll
        for (int kc = 0; kc < 8; ++kc)
            breg[c][kc] = *(const bf16x8*)(Bt + (size_t)(col0 + c * 16 + l15) * 256 +
                                           kc * 32 + lk * 8);

    f32x4 acc[4][2];
#pragma unroll
    for (int rc = 0; rc < 4; ++rc) {
        acc[rc][0] = (f32x4)0.0f;
        acc[rc][1] = (f32x4)0.0f;
    }

#pragma unroll
    for (int rc = 0; rc < 4; ++rc) {
        const int arow = rbase + rc * 16 + l15;
        const bool ok = arow < nrows;
        bf16x8 a[8];
        if (ok) {
            if (A1BF16) {
                const unsigned short* A1 = (const unsigned short*)A1v;
#pragma unroll
                for (int kc = 0; kc < 4; ++kc) {
                    a[kc] = *(const bf16x8*)(A1 + (size_t)arow * NF + kc * 32 + lk * 8);
                    a[kc + 4] = *(const bf16x8*)(A2 + (size_t)arow * NF + kc * 32 + lk * 8);
                }
            } else {
                const float* A1 = (const float*)A1v;
#pragma unroll
                for (int kc = 0; kc < 4; ++kc) {
                    const float* p = A1 + (size_t)arow * NF + kc * 32 + lk * 8;
                    float4 u = *(const float4*)p;
                    float4 v = *(const float4*)(p + 4);
                    a[kc][0] = (short)f2bf(u.x); a[kc][1] = (short)f2bf(u.y);
                    a[kc][2] = (short)f2bf(u.z); a[kc][3] = (short)f2bf(u.w);
                    a[kc][4] = (short)f2bf(v.x); a[kc][5] = (short)f2bf(v.y);
                    a[kc][6] = (short)f2bf(v.z); a[kc][7] = (short)f2bf(v.w);
                    a[kc + 4] = *(const bf16x8*)(A2 + (size_t)arow * NF + kc * 32 + lk * 8);
                }
            }
        } else {
#pragma unroll
            for (int kc = 0; kc < 8; ++kc) a[kc] = (bf16x8)(short)0;
        }
#pragma unroll
        for (int kc = 0; kc < 8; ++kc) {
            acc[rc][0] = __builtin_amdgcn_mfma_f32_16x16x32_bf16(a[kc], breg[0][kc],
                                                                 acc[rc][0], 0, 0, 0);
            acc[rc][1] = __builtin_amdgcn_mfma_f32_16x16x32_bf16(a[kc], breg[1][kc],
                                                                 acc[rc][1], 0, 0, 0);
        }
    }

#pragma unroll
    for (int rc = 0; rc < 4; ++rc) {
#pragma unroll
        for (int r = 0; r < 4; ++r) {
            const int orow = rbase + rc * 16 + lk * 4 + r;
            if (orow >= nrows) continue;
#pragma unroll
            for (int c = 0; c < 2; ++c) {
                float v = acc[rc][c][r];
                if (RELU) v = fmaxf(v, 0.f);
                const int col = col0 + c * 16 + l15;
                if (OUTBF16)
                    ((unsigned short*)outv)[(size_t)orow * NF + col] = f2bf(v);
                else
                    ((float*)outv)[(size_t)orow * NF + col] = v;
            }
        }
    }
}

extern "C" void kernel_launch(void* const* d_in, const int* in_sizes, int n_in,
                              void* d_out, int out_size, void* d_ws, size_t ws_size,
                              hipStream_t stream) {
    const float* x = (const float*)d_in[0];
    const float* W_in = (const float*)d_in[1];
    const float* W_out = (const float*)d_in[2];
    const int* src = (const int*)d_in[3];
    const int* dst = (const int*)d_in[4];

    const int n = in_sizes[0] / NF;  // 100000  (must stay < 2^24 for packed CSR)
    const int E = in_sizes[3];       // 1600000
    float* outp = (float*)d_out;

    const int NB = (n + 255) >> NBSHIFT;
    const int nchunks = (E + CHUNK - 1) / CHUNK;

    // workspace carve
    char* ws = (char*)d_ws;
    size_t off = 0;
    auto take = [&](size_t bytes) {
        void* p = ws + off;
        off = (off + bytes + 511) & ~(size_t)511;
        return p;
    };
    int* gbhist = (int*)take((size_t)NB * 4);
    int* bbase = (int*)take((size_t)(NB + 1) * 4);
    int* gcursor = (int*)take((size_t)NB * 4);
    int* offsets = (int*)take((size_t)(n + 1) * 4);
    float* invdeg = (float*)take((size_t)n * 4);
    unsigned short* BtIn = (unsigned short*)take(128 * 256 * 2);
    unsigned short* BtOut = (unsigned short*)take(128 * 256 * 2);
    unsigned* gpairs = (unsigned*)take((size_t)E * 4);
    int* esrc = (int*)take((size_t)E * 4);
    unsigned short* hb = (unsigned short*)take((size_t)n * NF * 2);
    unsigned short* neigh = (unsigned short*)take((size_t)n * NF * 2);
    unsigned char* degb = (unsigned char*)take((size_t)n);
    int* gdhist = (int*)take(256 * 4);
    int* dcur = (int*)take(256 * 4);
    int* dorder = (int*)take((size_t)n * 4);
    size_t need_fp8 = off + (size_t)n * NF * 2 + 512 + (size_t)n * NF + 512 +
                      (size_t)n * NF + 512;
    bool use_fp8 = (ws_size >= need_fp8);
    unsigned short* xb = nullptr;
    unsigned char* xq = nullptr;
    unsigned char* hq = nullptr;
    if (use_fp8) {
        xb = (unsigned short*)take((size_t)n * NF * 2);
        xq = (unsigned char*)take((size_t)n * NF);
        hq = (unsigned char*)take((size_t)n * NF);
    }
    bool use_xb = use_fp8 || (ws_size >= off + (size_t)n * NF * 2);
    if (!use_fp8 && use_xb) xb = (unsigned short*)take((size_t)n * NF * 2);

    // ---- fused prep (bhist | buildBt | x->bf16+fp8) + CSR build ----
    hipMemsetAsync(gbhist, 0, (size_t)NB * 4, stream);
    hipMemsetAsync(gdhist, 0, 256 * 4, stream);
    const int cvtBlocks = use_fp8 ? (int)(((long long)n * NF / 8 + 255) / 256) : 0;
    k_prep<<<BH + BT + cvtBlocks, 256, 0, stream>>>(dst, E, NB, gbhist, x, xb, xq,
                                                    W_in, W_out, BtIn, BtOut);
    k_bscan<<<1, 256, 0, stream>>>(gbhist, bbase, gcursor, NB, E, offsets, n);
    k_bucket<<<nchunks, 256, 0, stream>>>(src, dst, gcursor, gpairs, E);
    k_bsort<<<NB, 256, 0, stream>>>(gpairs, bbase, offsets, invdeg, degb, gdhist, esrc, n);

    const int gemmBlocks = (n + 63) / 64;

    if (use_fp8) {
        // degree counting-sort -> dorder (multisplit, low-contention)
        k_dscan<<<1, 256, 0, stream>>>(gdhist, dcur);
        k_dorder<<<(n + DCHUNK - 1) / DCHUNK, 256, 0, stream>>>(degb, dcur, dorder, n);

        const int agg4Blocks = (n + 15) / 16;  // 16 nodes per 256-thread block
        // ---- layer 0 ----
        k_agg4<<<agg4Blocks, 256, 0, stream>>>(xq, esrc, offsets, invdeg, dorder, neigh, n);
        k_gemm_lds<true, true, true>
            <<<gemmBlocks, 256, 0, stream>>>(xb, neigh, BtIn, hb, hq, n);
        // ---- layer 1 ----
        k_agg4<<<agg4Blocks, 256, 0, stream>>>(hq, esrc, offsets, invdeg, dorder, neigh, n);
        k_gemm_lds<false, false, false>
            <<<gemmBlocks, 256, 0, stream>>>(hb, neigh, BtOut, outp, nullptr, n);
    } else {
        const int aggBlocks = (n + 3) / 4;
        k_agg_f32<<<aggBlocks, 256, 0, stream>>>(x, esrc, offsets, invdeg, neigh, n);
        k_gemm_mfma<true, false, true>
            <<<gemmBlocks, 256, 0, stream>>>(x, neigh, BtIn, hb, n);
        k_agg_bf16<<<aggBlocks, 256, 0, stream>>>(hb, esrc, offsets, invdeg, neigh, n);
        k_gemm_mfma<false, true, false>
            <<<gemmBlocks, 256, 0, stream>>>(hb, neigh, BtOut, outp, n);
    }
}

// Round 13
// 199.112 us; speedup vs baseline: 3.5769x; 1.0154x over previous
//
#include <hip/hip_runtime.h>

#define NF 128
#define NBSHIFT 8        // 256 nodes per bucket
#define NBMAX 512        // padded bucket count for scans
#define CHUNK 4096       // edges per multisplit chunk
#define DCHUNK 4096      // nodes per degree-multisplit chunk

typedef __attribute__((ext_vector_type(8))) short bf16x8;
typedef __attribute__((ext_vector_type(4))) float f32x4;
typedef __attribute__((ext_vector_type(2))) float f32x2;

__device__ __forceinline__ unsigned short f2bf(float f) {
    unsigned int u = __builtin_bit_cast(unsigned int, f);
    u = (u + 0x7fffu + ((u >> 16) & 1u)) >> 16;
    return (unsigned short)u;
}
__device__ __forceinline__ float bflo(unsigned int u) {
    return __builtin_bit_cast(float, u << 16);
}
__device__ __forceinline__ float bfhi(unsigned int u) {
    return __builtin_bit_cast(float, u & 0xffff0000u);
}
__device__ __forceinline__ unsigned char f2fp8(float v) {
    return (unsigned char)(__builtin_amdgcn_cvt_pk_fp8_f32(v, v, 0, false) & 0xff);
}

// ================= tiny zero kernel (replaces pathological hipMemsetAsync fills) ======
__global__ void k_zero(int* __restrict__ a, int na, int* __restrict__ b, int nb) {
    int i = blockIdx.x * blockDim.x + threadIdx.x;
    if (i < na) a[i] = 0;
    if (i < nb) b[i] = 0;
}

// ================= fused prep: bhist | buildBt | cvt(x -> bf16 + fp8) =================
#define BH 256
#define BT 256
__global__ __launch_bounds__(256) void k_prep(const int* __restrict__ dst, int E, int NB,
                                              int* __restrict__ gbhist,
                                              const float* __restrict__ x,
                                              unsigned short* __restrict__ xb,
                                              unsigned char* __restrict__ xq,
                                              const float* __restrict__ Win,
                                              const float* __restrict__ Wout,
                                              unsigned short* __restrict__ BtIn,
                                              unsigned short* __restrict__ BtOut) {
    __shared__ int lh[NBMAX];
    const int bb = blockIdx.x;
    const int t = threadIdx.x;
    if (bb < BH) {
        for (int k = t; k < NBMAX; k += 256) lh[k] = 0;
        __syncthreads();
        for (int i = bb * 256 + t; i < E; i += BH * 256)
            atomicAdd(&lh[((unsigned)dst[i]) >> NBSHIFT], 1);
        __syncthreads();
        for (int k = t; k < NB; k += 256)
            if (lh[k]) atomicAdd(&gbhist[k], lh[k]);
    } else if (bb < BH + BT) {
        int b2 = bb - BH;
        const float* W = (b2 < 128) ? Win : Wout;
        unsigned short* Bt = (b2 < 128) ? BtIn : BtOut;
        int idx = (b2 & 127) * 256 + t;
        int c = idx >> 8;
        int k = idx & 255;
        int p = k >> 7, kk = k & 127;
        Bt[idx] = f2bf(W[((size_t)p * NF + kk) * NF + c]);
    } else {
        long long i = (long long)(bb - BH - BT) * 256 + t;
        const float4 a = *reinterpret_cast<const float4*>(x + i * 8);
        const float4 b = *reinterpret_cast<const float4*>(x + i * 8 + 4);
        union { unsigned short s[8]; uint4 u; } o;
        o.s[0] = f2bf(a.x); o.s[1] = f2bf(a.y); o.s[2] = f2bf(a.z); o.s[3] = f2bf(a.w);
        o.s[4] = f2bf(b.x); o.s[5] = f2bf(b.y); o.s[6] = f2bf(b.z); o.s[7] = f2bf(b.w);
        *reinterpret_cast<uint4*>(xb + i * 8) = o.u;
        int lo = __builtin_amdgcn_cvt_pk_fp8_f32(a.x, a.y, 0, false);
        lo = __builtin_amdgcn_cvt_pk_fp8_f32(a.z, a.w, lo, true);
        int hi = __builtin_amdgcn_cvt_pk_fp8_f32(b.x, b.y, 0, false);
        hi = __builtin_amdgcn_cvt_pk_fp8_f32(b.z, b.w, hi, true);
        uint2 oq; oq.x = (unsigned)lo; oq.y = (unsigned)hi;
        *reinterpret_cast<uint2*>(xq + i * 8) = oq;
    }
}

// ================= CSR build =================

__global__ __launch_bounds__(256) void k_bscan(const int* __restrict__ gbhist,
                                               int* __restrict__ bbase, int* __restrict__ gcursor,
                                               int NB, int E, int* __restrict__ offsets, int n) {
    __shared__ int sA[NBMAX], sB[NBMAX];
    int t = threadIdx.x;
    for (int k = t; k < NBMAX; k += 256) sA[k] = (k < NB) ? gbhist[k] : 0;
    __syncthreads();
    int* pin = sA;
    int* pout = sB;
    for (int off = 1; off < NBMAX; off <<= 1) {
        for (int k = t; k < NBMAX; k += 256) pout[k] = pin[k] + (k >= off ? pin[k - off] : 0);
        __syncthreads();
        int* tmp = pin; pin = pout; pout = tmp;
    }
    for (int k = t; k < NB; k += 256) {
        int excl = pin[k] - gbhist[k];
        bbase[k] = excl;
        gcursor[k] = excl;
    }
    if (t == 0) {
        bbase[NB] = E;
        offsets[n] = E;
    }
}

// chunked multisplit; edge packed 32-bit: (dst&255)<<24 | src  (needs n < 2^24)
__global__ __launch_bounds__(256) void k_bucket(const int* __restrict__ src,
                                                const int* __restrict__ dst,
                                                int* __restrict__ gcursor,
                                                unsigned* __restrict__ gpairs, int E) {
    __shared__ int lhist[NBMAX], lbase[NBMAX], lcur[NBMAX], gb[NBMAX];
    __shared__ int sA[NBMAX], sB[NBMAX];
    __shared__ unsigned stage[CHUNK];
    __shared__ unsigned short stage_b[CHUNK];
    const int t = threadIdx.x;
    const int c0 = blockIdx.x * CHUNK;
    const int cc = min(CHUNK, E - c0);

    for (int k = t; k < NBMAX; k += 256) lhist[k] = 0;
    __syncthreads();

    int ls[16], ld[16];
#pragma unroll
    for (int j = 0; j < 16; ++j) {
        int i = t + j * 256;
        ls[j] = 0; ld[j] = 0;
        if (i < cc) {
            ls[j] = src[c0 + i];
            ld[j] = dst[c0 + i];
            atomicAdd(&lhist[((unsigned)ld[j]) >> NBSHIFT], 1);
        }
    }
    __syncthreads();
    for (int k = t; k < NBMAX; k += 256) sA[k] = lhist[k];
    __syncthreads();
    int* pin = sA;
    int* pout = sB;
    for (int off = 1; off < NBMAX; off <<= 1) {
        for (int k = t; k < NBMAX; k += 256) pout[k] = pin[k] + (k >= off ? pin[k - off] : 0);
        __syncthreads();
        int* tmp = pin; pin = pout; pout = tmp;
    }
    for (int k = t; k < NBMAX; k += 256) {
        int excl = pin[k] - lhist[k];
        lbase[k] = excl;
        lcur[k] = excl;
        int cnt = lhist[k];
        if (cnt > 0) gb[k] = atomicAdd(&gcursor[k], cnt);
    }
    __syncthreads();
#pragma unroll
    for (int j = 0; j < 16; ++j) {
        int i = t + j * 256;
        if (i < cc) {
            int b = ((unsigned)ld[j]) >> NBSHIFT;
            int pos = atomicAdd(&lcur[b], 1);
            stage[pos] = (((unsigned)ld[j] & 255u) << 24) | (unsigned)ls[j];
            stage_b[pos] = (unsigned short)b;
        }
    }
    __syncthreads();
    for (int idx = t; idx < cc; idx += 256) {
        unsigned p = stage[idx];
        int b = stage_b[idx];
        gpairs[gb[b] + (idx - lbase[b])] = p;
    }
}

// per-bucket: per-node hist + scan -> offsets/invdeg/degb, LDS-privatized global
// degree histogram, scatter esrc in bucket
__global__ __launch_bounds__(256) void k_bsort(const unsigned* __restrict__ gpairs,
                                               const int* __restrict__ bbase,
                                               int* __restrict__ offsets,
                                               float* __restrict__ invdeg,
                                               unsigned char* __restrict__ degb,
                                               int* __restrict__ gdhist,
                                               int* __restrict__ esrc, int n) {
    __shared__ int lcnt[256], lcur[256], sA[256], sB[256], ldh[256];
    const int b = blockIdx.x;
    const int t = threadIdx.x;
    const int base = bbase[b];
    const int c = bbase[b + 1] - base;
    const int n0 = b << NBSHIFT;

    lcnt[t] = 0;
    ldh[t] = 0;
    __syncthreads();
    for (int i = t; i < c; i += 256) {
        int node = (int)(gpairs[base + i] >> 24);
        atomicAdd(&lcnt[node], 1);
    }
    __syncthreads();
    sA[t] = lcnt[t];
    __syncthreads();
    int* pin = sA;
    int* pout = sB;
    for (int off = 1; off < 256; off <<= 1) {
        pout[t] = pin[t] + (t >= off ? pin[t - off] : 0);
        __syncthreads();
        int* tmp = pin; pin = pout; pout = tmp;
    }
    int excl = pin[t] - lcnt[t];
    lcur[t] = excl;
    int node_g = n0 + t;
    if (node_g < n) {
        offsets[node_g] = base + excl;
        invdeg[node_g] = 1.0f / (float)max(lcnt[t], 1);
        int d = min(lcnt[t], 255);
        degb[node_g] = (unsigned char)d;
        atomicAdd(&ldh[d], 1);   // LDS-privatized degree histogram
    }
    __syncthreads();
    if (ldh[t] > 0) atomicAdd(&gdhist[t], ldh[t]);  // <=256 global atomics/block
    for (int i = t; i < c; i += 256) {
        unsigned p = gpairs[base + i];
        int node = (int)(p >> 24);
        int pos = atomicAdd(&lcur[node], 1);
        esrc[base + pos] = (int)(p & 0x00ffffffu);
    }
}

// degree counting-sort pass 1: scan 256-bin hist -> global cursors (exclusive bases)
__global__ void k_dscan(const int* __restrict__ gdhist, int* __restrict__ dcur) {
    __shared__ int sh[256];
    int t = threadIdx.x;
    int v = gdhist[t];
    sh[t] = v;
    __syncthreads();
    for (int off = 1; off < 256; off <<= 1) {
        int x = (t >= off) ? sh[t - off] : 0;
        __syncthreads();
        sh[t] += x;
        __syncthreads();
    }
    dcur[t] = sh[t] - v;  // exclusive base
}

// degree counting-sort pass 2: chunked multisplit (one cursor atomic per bin per block)
__global__ __launch_bounds__(256) void k_dorder(const unsigned char* __restrict__ degb,
                                                int* __restrict__ dcur,
                                                int* __restrict__ dorder, int n) {
    __shared__ int lhist[256], lbase[256], lcur[256], gb[256], sA[256], sB[256];
    __shared__ int stageN[DCHUNK];
    __shared__ unsigned char stageD[DCHUNK];
    const int t = threadIdx.x;
    const int c0 = blockIdx.x * DCHUNK;
    const int cc = min(DCHUNK, n - c0);

    lhist[t] = 0;
    __syncthreads();
    int dloc[16];
#pragma unroll
    for (int j = 0; j < 16; ++j) {
        int i = t + j * 256;
        dloc[j] = -1;
        if (i < cc) {
            dloc[j] = degb[c0 + i];
            atomicAdd(&lhist[dloc[j]], 1);
        }
    }
    __syncthreads();
    sA[t] = lhist[t];
    __syncthreads();
    int* pin = sA;
    int* pout = sB;
    for (int off = 1; off < 256; off <<= 1) {
        pout[t] = pin[t] + (t >= off ? pin[t - off] : 0);
        __syncthreads();
        int* tmp = pin; pin = pout; pout = tmp;
    }
    int excl = pin[t] - lhist[t];
    lbase[t] = excl;
    lcur[t] = excl;
    if (lhist[t] > 0) gb[t] = atomicAdd(&dcur[t], lhist[t]);
    __syncthreads();
#pragma unroll
    for (int j = 0; j < 16; ++j) {
        int i = t + j * 256;
        if (i < cc) {
            int d = dloc[j];
            int pos = atomicAdd(&lcur[d], 1);
            stageN[pos] = c0 + i;
            stageD[pos] = (unsigned char)d;
        }
    }
    __syncthreads();
    for (int idx = t; idx < cc; idx += 256) {
        int d = stageD[idx];
        dorder[gb[d] + (idx - lbase[d])] = stageN[idx];
    }
}

// ================= gather aggregation: 4 nodes per wave, fp8 source ==============
__global__ __launch_bounds__(256) void k_agg4(const unsigned char* __restrict__ feat,
                                              const int* __restrict__ esrc,
                                              const int* __restrict__ offsets,
                                              const float* __restrict__ invdeg,
                                              const int* __restrict__ dorder,
                                              unsigned short* __restrict__ neigh, int n) {
    const int tid = threadIdx.x;
    const int wv = (int)(((long long)blockIdx.x * blockDim.x + tid) >> 6);
    if (wv * 4 >= n) return;
    const int lane = tid & 63;
    const int g = lane >> 4;
    const int q = lane & 15;
    const int i4 = wv * 4 + g;

    int node = 0, beg = 0, deg = 0;
    if (i4 < n) {
        node = dorder[i4];
        beg = offsets[node];
        deg = offsets[node + 1] - beg;
    }
    int mn = deg, mx = deg;
    int s1 = __shfl_xor(mn, 16); mn = min(mn, s1);
    int s2 = __shfl_xor(mx, 16); mx = max(mx, s2);
    s1 = __shfl_xor(mn, 32); mn = min(mn, s1);
    s2 = __shfl_xor(mx, 32); mx = max(mx, s2);
    const int mindeg = __builtin_amdgcn_readfirstlane(mn);
    const int maxdeg = __builtin_amdgcn_readfirstlane(mx);

    const unsigned qoff = (unsigned)q * 8u;
    f32x2 c01 = {0.f, 0.f}, c23 = {0.f, 0.f}, c45 = {0.f, 0.f}, c67 = {0.f, 0.f};

    int i = 0;
    for (; i + 4 <= mindeg; i += 4) {
        int e0 = esrc[beg + i + 0];
        int e1 = esrc[beg + i + 1];
        int e2 = esrc[beg + i + 2];
        int e3 = esrc[beg + i + 3];
        uint2 v0 = *(const uint2*)(feat + (unsigned)e0 * 128u + qoff);
        uint2 v1 = *(const uint2*)(feat + (unsigned)e1 * 128u + qoff);
        uint2 v2 = *(const uint2*)(feat + (unsigned)e2 * 128u + qoff);
        uint2 v3 = *(const uint2*)(feat + (unsigned)e3 * 128u + qoff);
        c01 += __builtin_amdgcn_cvt_pk_f32_fp8((int)v0.x, false);
        c23 += __builtin_amdgcn_cvt_pk_f32_fp8((int)v0.x, true);
        c45 += __builtin_amdgcn_cvt_pk_f32_fp8((int)v0.y, false);
        c67 += __builtin_amdgcn_cvt_pk_f32_fp8((int)v0.y, true);
        c01 += __builtin_amdgcn_cvt_pk_f32_fp8((int)v1.x, false);
        c23 += __builtin_amdgcn_cvt_pk_f32_fp8((int)v1.x, true);
        c45 += __builtin_amdgcn_cvt_pk_f32_fp8((int)v1.y, false);
        c67 += __builtin_amdgcn_cvt_pk_f32_fp8((int)v1.y, true);
        c01 += __builtin_amdgcn_cvt_pk_f32_fp8((int)v2.x, false);
        c23 += __builtin_amdgcn_cvt_pk_f32_fp8((int)v2.x, true);
        c45 += __builtin_amdgcn_cvt_pk_f32_fp8((int)v2.y, false);
        c67 += __builtin_amdgcn_cvt_pk_f32_fp8((int)v2.y, true);
        c01 += __builtin_amdgcn_cvt_pk_f32_fp8((int)v3.x, false);
        c23 += __builtin_amdgcn_cvt_pk_f32_fp8((int)v3.x, true);
        c45 += __builtin_amdgcn_cvt_pk_f32_fp8((int)v3.y, false);
        c67 += __builtin_amdgcn_cvt_pk_f32_fp8((int)v3.y, true);
    }
    for (; i < maxdeg; ++i) {
        if (i < deg) {
            int e = esrc[beg + i];
            uint2 v = *(const uint2*)(feat + (unsigned)e * 128u + qoff);
            c01 += __builtin_amdgcn_cvt_pk_f32_fp8((int)v.x, false);
            c23 += __builtin_amdgcn_cvt_pk_f32_fp8((int)v.x, true);
            c45 += __builtin_amdgcn_cvt_pk_f32_fp8((int)v.y, false);
            c67 += __builtin_amdgcn_cvt_pk_f32_fp8((int)v.y, true);
        }
    }

    if (i4 < n) {
        const float sc = invdeg[node];
        float a0 = c01.x * sc, a1 = c01.y * sc, a2 = c23.x * sc, a3 = c23.y * sc;
        float a4 = c45.x * sc, a5 = c45.y * sc, a6 = c67.x * sc, a7 = c67.y * sc;
        unsigned p0, p1, p2, p3;
        asm("v_cvt_pk_bf16_f32 %0, %1, %2" : "=v"(p0) : "v"(a0), "v"(a1));
        asm("v_cvt_pk_bf16_f32 %0, %1, %2" : "=v"(p1) : "v"(a2), "v"(a3));
        asm("v_cvt_pk_bf16_f32 %0, %1, %2" : "=v"(p2) : "v"(a4), "v"(a5));
        asm("v_cvt_pk_bf16_f32 %0, %1, %2" : "=v"(p3) : "v"(a6), "v"(a7));
        uint4 o; o.x = p0; o.y = p1; o.z = p2; o.w = p3;
        *(uint4*)((char*)neigh + (size_t)node * 256 + (unsigned)q * 16u) = o;
    }
}

// fallback bf16-source aggregate (non-fp8 path)
__global__ __launch_bounds__(256) void k_agg_bf16(const unsigned short* __restrict__ feat,
                                                  const int* __restrict__ esrc,
                                                  const int* __restrict__ offsets,
                                                  const float* __restrict__ invdeg,
                                                  unsigned short* __restrict__ neigh, int n) {
    int wid0 = (int)(((long long)blockIdx.x * blockDim.x + threadIdx.x) >> 6);
    const int wid = __builtin_amdgcn_readfirstlane(wid0);
    if (wid >= n) return;
    const int lane = threadIdx.x & 63;
    const int g = lane >> 4;
    const int q = lane & 15;
    const unsigned qoff = (unsigned)q * 16u;
    const char* fb = (const char*)feat;
    const int beg = offsets[wid];
    const int end = offsets[wid + 1];
    float a0 = 0.f, a1 = 0.f, a2 = 0.f, a3 = 0.f, a4 = 0.f, a5 = 0.f, a6 = 0.f, a7 = 0.f;
    int i = beg;
    for (; i + 4 <= end; i += 4) {
        int e0 = esrc[i + 0], e1 = esrc[i + 1], e2 = esrc[i + 2], e3 = esrc[i + 3];
        int es = (g & 2) ? ((g & 1) ? e3 : e2) : ((g & 1) ? e1 : e0);
        uint4 v = *(const uint4*)(fb + (unsigned)es * 256u + qoff);
        a0 += bflo(v.x); a1 += bfhi(v.x);
        a2 += bflo(v.y); a3 += bfhi(v.y);
        a4 += bflo(v.z); a5 += bfhi(v.z);
        a6 += bflo(v.w); a7 += bfhi(v.w);
    }
    if (i < end) {
        int r = end - i;
        if (g < r) {
            int es = esrc[i + g];
            uint4 v = *(const uint4*)(fb + (unsigned)es * 256u + qoff);
            a0 += bflo(v.x); a1 += bfhi(v.x);
            a2 += bflo(v.y); a3 += bfhi(v.y);
            a4 += bflo(v.z); a5 += bfhi(v.z);
            a6 += bflo(v.w); a7 += bfhi(v.w);
        }
    }
    a0 += __shfl_xor(a0, 16); a1 += __shfl_xor(a1, 16);
    a2 += __shfl_xor(a2, 16); a3 += __shfl_xor(a3, 16);
    a4 += __shfl_xor(a4, 16); a5 += __shfl_xor(a5, 16);
    a6 += __shfl_xor(a6, 16); a7 += __shfl_xor(a7, 16);
    a0 += __shfl_xor(a0, 32); a1 += __shfl_xor(a1, 32);
    a2 += __shfl_xor(a2, 32); a3 += __shfl_xor(a3, 32);
    a4 += __shfl_xor(a4, 32); a5 += __shfl_xor(a5, 32);
    a6 += __shfl_xor(a6, 32); a7 += __shfl_xor(a7, 32);
    const float sc = invdeg[wid];
    a0 *= sc; a1 *= sc; a2 *= sc; a3 *= sc;
    a4 *= sc; a5 *= sc; a6 *= sc; a7 *= sc;
    unsigned p0, p1, p2, p3;
    asm("v_cvt_pk_bf16_f32 %0, %1, %2" : "=v"(p0) : "v"(a0), "v"(a1));
    asm("v_cvt_pk_bf16_f32 %0, %1, %2" : "=v"(p1) : "v"(a2), "v"(a3));
    asm("v_cvt_pk_bf16_f32 %0, %1, %2" : "=v"(p2) : "v"(a4), "v"(a5));
    asm("v_cvt_pk_bf16_f32 %0, %1, %2" : "=v"(p3) : "v"(a6), "v"(a7));
    if (g == 0) {
        uint4 o; o.x = p0; o.y = p1; o.z = p2; o.w = p3;
        *(uint4*)((char*)neigh + (size_t)wid * 256 + qoff) = o;
    }
}

// fallback fp32-source aggregate
__global__ __launch_bounds__(256) void k_agg_f32(const float* __restrict__ feat,
                                                 const int* __restrict__ esrc,
                                                 const int* __restrict__ offsets,
                                                 const float* __restrict__ invdeg,
                                                 unsigned short* __restrict__ neigh, int n) {
    int wid0 = (int)(((long long)blockIdx.x * blockDim.x + threadIdx.x) >> 6);
    const int wid = __builtin_amdgcn_readfirstlane(wid0);
    if (wid >= n) return;
    int lane = threadIdx.x & 63;
    int beg = offsets[wid], end = offsets[wid + 1];
    float a0 = 0.f, a1 = 0.f;
    for (int i = beg; i < end; ++i) {
        int s0 = esrc[i];
        float2 v0 = *(const float2*)(feat + (size_t)s0 * NF + lane * 2);
        a0 += v0.x; a1 += v0.y;
    }
    float sc = invdeg[wid];
    unsigned pk;
    float ca = a0 * sc, cb = a1 * sc;
    asm("v_cvt_pk_bf16_f32 %0, %1, %2" : "=v"(pk) : "v"(ca), "v"(cb));
    *(unsigned*)(neigh + (size_t)wid * NF + lane * 2) = pk;
}

// ================= MFMA GEMM, LDS-staged (fp8 path) =================
template <bool RELU, bool OUTBF16, bool WRITEQ>
__global__ __launch_bounds__(256) void k_gemm_lds(const unsigned short* __restrict__ A1,
                                                  const unsigned short* __restrict__ A2,
                                                  const unsigned short* __restrict__ Bt,
                                                  void* __restrict__ outv,
                                                  unsigned char* __restrict__ outq,
                                                  int nrows) {
    __shared__ __align__(16) unsigned char sm[32768];  // [2][64 rows][128 k] bf16
    const int tid = threadIdx.x;
    const int w = tid >> 6;
    const int lane = tid & 63;
    const int l15 = lane & 15;
    const int lk = lane >> 4;  // 0..3
    const int col0 = w * 32;
    const int rbase = blockIdx.x * 64;

#pragma unroll
    for (int h = 0; h < 2; ++h) {
        const unsigned short* Ah = h ? A2 : A1;
#pragma unroll
        for (int j = 0; j < 4; ++j) {
            const int r = w * 16 + j * 4 + lk;
            const int garow = min(rbase + r, nrows - 1);
            const int cch = l15 ^ (r & 7);
            const unsigned short* srcp = Ah + (size_t)garow * NF + cch * 8;
            unsigned char* ldst = &sm[h * 16384 + (w * 16 + j * 4) * 256];
            __builtin_amdgcn_global_load_lds(
                (const __attribute__((address_space(1))) void*)srcp,
                (__attribute__((address_space(3))) void*)ldst, 16, 0, 0);
        }
    }

    bf16x8 breg[2][8];
#pragma unroll
    for (int c = 0; c < 2; ++c)
#pragma unroll
        for (int kc = 0; kc < 8; ++kc)
            breg[c][kc] = *(const bf16x8*)(Bt + (size_t)(col0 + c * 16 + l15) * 256 +
                                           kc * 32 + lk * 8);

    f32x4 acc[4][2];
#pragma unroll
    for (int rc = 0; rc < 4; ++rc) {
        acc[rc][0] = (f32x4)0.0f;
        acc[rc][1] = (f32x4)0.0f;
    }

    __syncthreads();

#pragma unroll
    for (int rc = 0; rc < 4; ++rc) {
        const int row = rc * 16 + l15;
#pragma unroll
        for (int kc = 0; kc < 8; ++kc) {
            const int half = kc >> 2;
            const int kk = kc & 3;
            const int chunk = (kk * 4 + lk) ^ (row & 7);
            const bf16x8 a = *(const bf16x8*)&sm[half * 16384 + row * 256 + chunk * 16];
            acc[rc][0] = __builtin_amdgcn_mfma_f32_16x16x32_bf16(a, breg[0][kc],
                                                                 acc[rc][0], 0, 0, 0);
            acc[rc][1] = __builtin_amdgcn_mfma_f32_16x16x32_bf16(a, breg[1][kc],
                                                                 acc[rc][1], 0, 0, 0);
        }
    }

    __syncthreads();

    if (OUTBF16) {
        unsigned short* smb = (unsigned short*)sm;
        unsigned char* smq = sm + 16384;
#pragma unroll
        for (int rc = 0; rc < 4; ++rc)
#pragma unroll
            for (int r = 0; r < 4; ++r) {
                const int row = rc * 16 + lk * 4 + r;
#pragma unroll
                for (int c = 0; c < 2; ++c) {
                    float v = acc[rc][c][r];
                    if (RELU) v = fmaxf(v, 0.f);
                    const int col = col0 + c * 16 + l15;
                    smb[row * NF + col] = f2bf(v);
                    if (WRITEQ) smq[row * NF + col] = f2fp8(v);
                }
            }
        __syncthreads();
#pragma unroll
        for (int it = 0; it < 4; ++it) {
            const int off = (tid + it * 256) * 16;
            if (rbase + (off >> 8) < nrows)
                *(uint4*)((char*)outv + (size_t)rbase * 256 + off) =
                    *(const uint4*)&sm[off];
        }
        if (WRITEQ) {
#pragma unroll
            for (int it = 0; it < 2; ++it) {
                const int off = (tid + it * 256) * 16;
                if (rbase + (off >> 7) < nrows)
                    *(uint4*)(outq + (size_t)rbase * 128 + off) =
                        *(const uint4*)&sm[16384 + off];
            }
        }
    } else {
        float* smf = (float*)sm;
#pragma unroll
        for (int rc = 0; rc < 4; ++rc)
#pragma unroll
            for (int r = 0; r < 4; ++r) {
                const int row = rc * 16 + lk * 4 + r;
#pragma unroll
                for (int c = 0; c < 2; ++c) {
                    float v = acc[rc][c][r];
                    if (RELU) v = fmaxf(v, 0.f);
                    smf[row * NF + col0 + c * 16 + l15] = v;
                }
            }
        __syncthreads();
#pragma unroll
        for (int it = 0; it < 8; ++it) {
            const int off = (tid + it * 256) * 16;
            if (rbase + (off >> 9) < nrows)
                *(uint4*)((char*)outv + (size_t)rbase * 512 + off) =
                    *(const uint4*)&sm[off];
        }
    }
}

// ================= fallback GEMM (non-fp8 path) =================
template <bool RELU, bool A1BF16, bool OUTBF16>
__global__ __launch_bounds__(256) void k_gemm_mfma(const void* __restrict__ A1v,
                                                   const unsigned short* __restrict__ A2,
                                                   const unsigned short* __restrict__ Bt,
                                                   void* __restrict__ outv, int nrows) {
    const int tid = threadIdx.x;
    const int wave = tid >> 6;
    const int lane = tid & 63;
    const int l15 = lane & 15;
    const int lk = lane >> 4;
    const int col0 = wave * 32;
    const int rbase = blockIdx.x * 64;

    bf16x8 breg[2][8];
#pragma unroll
    for (int c = 0; c < 2; ++c)
#pragma unroll
        for (int kc = 0; kc < 8; ++kc)
            breg[c][kc] = *(const bf16x8*)(Bt + (size_t)(col0 + c * 16 + l15) * 256 +
                                           kc * 32 + lk * 8);

    f32x4 acc[4][2];
#pragma unroll
    for (int rc = 0; rc < 4; ++rc) {
        acc[rc][0] = (f32x4)0.0f;
        acc[rc][1] = (f32x4)0.0f;
    }

#pragma unroll
    for (int rc = 0; rc < 4; ++rc) {
        const int arow = rbase + rc * 16 + l15;
        const bool ok = arow < nrows;
        bf16x8 a[8];
        if (ok) {
            if (A1BF16) {
                const unsigned short* A1 = (const unsigned short*)A1v;
#pragma unroll
                for (int kc = 0; kc < 4; ++kc) {
                    a[kc] = *(const bf16x8*)(A1 + (size_t)arow * NF + kc * 32 + lk * 8);
                    a[kc + 4] = *(const bf16x8*)(A2 + (size_t)arow * NF + kc * 32 + lk * 8);
                }
            } else {
                const float* A1 = (const float*)A1v;
#pragma unroll
                for (int kc = 0; kc < 4; ++kc) {
                    const float* p = A1 + (size_t)arow * NF + kc * 32 + lk * 8;
                    float4 u = *(const float4*)p;
                    float4 v = *(const float4*)(p + 4);
                    a[kc][0] = (short)f2bf(u.x); a[kc][1] = (short)f2bf(u.y);
                    a[kc][2] = (short)f2bf(u.z); a[kc][3] = (short)f2bf(u.w);
                    a[kc][4] = (short)f2bf(v.x); a[kc][5] = (short)f2bf(v.y);
                    a[kc][6] = (short)f2bf(v.z); a[kc][7] = (short)f2bf(v.w);
                    a[kc + 4] = *(const bf16x8*)(A2 + (size_t)arow * NF + kc * 32 + lk * 8);
                }
            }
        } else {
#pragma unroll
            for (int kc = 0; kc < 8; ++kc) a[kc] = (bf16x8)(short)0;
        }
#pragma unroll
        for (int kc = 0; kc < 8; ++kc) {
            acc[rc][0] = __builtin_amdgcn_mfma_f32_16x16x32_bf16(a[kc], breg[0][kc],
                                                                 acc[rc][0], 0, 0, 0);
            acc[rc][1] = __builtin_amdgcn_mfma_f32_16x16x32_bf16(a[kc], breg[1][kc],
                                                                 acc[rc][1], 0, 0, 0);
        }
    }

#pragma unroll
    for (int rc = 0; rc < 4; ++rc) {
#pragma unroll
        for (int r = 0; r < 4; ++r) {
            const int orow = rbase + rc * 16 + lk * 4 + r;
            if (orow >= nrows) continue;
#pragma unroll
            for (int c = 0; c < 2; ++c) {
                float v = acc[rc][c][r];
                if (RELU) v = fmaxf(v, 0.f);
                const int col = col0 + c * 16 + l15;
                if (OUTBF16)
                    ((unsigned short*)outv)[(size_t)orow * NF + col] = f2bf(v);
                else
                    ((float*)outv)[(size_t)orow * NF + col] = v;
            }
        }
    }
}

extern "C" void kernel_launch(void* const* d_in, const int* in_sizes, int n_in,
                              void* d_out, int out_size, void* d_ws, size_t ws_size,
                              hipStream_t stream) {
    const float* x = (const float*)d_in[0];
    const float* W_in = (const float*)d_in[1];
    const float* W_out = (const float*)d_in[2];
    const int* src = (const int*)d_in[3];
    const int* dst = (const int*)d_in[4];

    const int n = in_sizes[0] / NF;  // 100000  (must stay < 2^24 for packed CSR)
    const int E = in_sizes[3];       // 1600000
    float* outp = (float*)d_out;

    const int NB = (n + 255) >> NBSHIFT;
    const int nchunks = (E + CHUNK - 1) / CHUNK;

    // workspace carve
    char* ws = (char*)d_ws;
    size_t off = 0;
    auto take = [&](size_t bytes) {
        void* p = ws + off;
        off = (off + bytes + 511) & ~(size_t)511;
        return p;
    };
    int* gbhist = (int*)take((size_t)NB * 4);
    int* bbase = (int*)take((size_t)(NB + 1) * 4);
    int* gcursor = (int*)take((size_t)NB * 4);
    int* offsets = (int*)take((size_t)(n + 1) * 4);
    float* invdeg = (float*)take((size_t)n * 4);
    unsigned short* BtIn = (unsigned short*)take(128 * 256 * 2);
    unsigned short* BtOut = (unsigned short*)take(128 * 256 * 2);
    unsigned* gpairs = (unsigned*)take((size_t)E * 4);
    int* esrc = (int*)take((size_t)E * 4);
    unsigned short* hb = (unsigned short*)take((size_t)n * NF * 2);
    unsigned short* neigh = (unsigned short*)take((size_t)n * NF * 2);
    unsigned char* degb = (unsigned char*)take((size_t)n);
    int* gdhist = (int*)take(256 * 4);
    int* dcur = (int*)take(256 * 4);
    int* dorder = (int*)take((size_t)n * 4);
    size_t need_fp8 = off + (size_t)n * NF * 2 + 512 + (size_t)n * NF + 512 +
                      (size_t)n * NF + 512;
    bool use_fp8 = (ws_size >= need_fp8);
    unsigned short* xb = nullptr;
    unsigned char* xq = nullptr;
    unsigned char* hq = nullptr;
    if (use_fp8) {
        xb = (unsigned short*)take((size_t)n * NF * 2);
        xq = (unsigned char*)take((size_t)n * NF);
        hq = (unsigned char*)take((size_t)n * NF);
    }
    bool use_xb = use_fp8 || (ws_size >= off + (size_t)n * NF * 2);
    if (!use_fp8 && use_xb) xb = (unsigned short*)take((size_t)n * NF * 2);

    // ---- zero counters (custom kernel; runtime memset fills cost ~40us each) ----
    k_zero<<<(max(NB, 256) + 255) / 256, 256, 0, stream>>>(gbhist, NB, gdhist, 256);

    // ---- fused prep (bhist | buildBt | x->bf16+fp8) + CSR build ----
    const int cvtBlocks = use_fp8 ? (int)(((long long)n * NF / 8 + 255) / 256) : 0;
    k_prep<<<BH + BT + cvtBlocks, 256, 0, stream>>>(dst, E, NB, gbhist, x, xb, xq,
                                                    W_in, W_out, BtIn, BtOut);
    k_bscan<<<1, 256, 0, stream>>>(gbhist, bbase, gcursor, NB, E, offsets, n);
    k_bucket<<<nchunks, 256, 0, stream>>>(src, dst, gcursor, gpairs, E);
    k_bsort<<<NB, 256, 0, stream>>>(gpairs, bbase, offsets, invdeg, degb, gdhist, esrc, n);

    const int gemmBlocks = (n + 63) / 64;

    if (use_fp8) {
        // degree counting-sort -> dorder (multisplit, low-contention)
        k_dscan<<<1, 256, 0, stream>>>(gdhist, dcur);
        k_dorder<<<(n + DCHUNK - 1) / DCHUNK, 256, 0, stream>>>(degb, dcur, dorder, n);

        const int agg4Blocks = (n + 15) / 16;  // 16 nodes per 256-thread block
        // ---- layer 0 ----
        k_agg4<<<agg4Blocks, 256, 0, stream>>>(xq, esrc, offsets, invdeg, dorder, neigh, n);
        k_gemm_lds<true, true, true>
            <<<gemmBlocks, 256, 0, stream>>>(xb, neigh, BtIn, hb, hq, n);
        // ---- layer 1 ----
        k_agg4<<<agg4Blocks, 256, 0, stream>>>(hq, esrc, offsets, invdeg, dorder, neigh, n);
        k_gemm_lds<false, false, false>
            <<<gemmBlocks, 256, 0, stream>>>(hb, neigh, BtOut, outp, nullptr, n);
    } else {
        const int aggBlocks = (n + 3) / 4;
        k_agg_f32<<<aggBlocks, 256, 0, stream>>>(x, esrc, offsets, invdeg, neigh, n);
        k_gemm_mfma<true, false, true>
            <<<gemmBlocks, 256, 0, stream>>>(x, neigh, BtIn, hb, n);
        k_agg_bf16<<<aggBlocks, 256, 0, stream>>>(hb, esrc, offsets, invdeg, neigh, n);
        k_gemm_mfma<false, true, false>
            <<<gemmBlocks, 256, 0, stream>>>(hb, neigh, BtOut, outp, n);
    }
}

// Round 14
// 196.706 us; speedup vs baseline: 3.6207x; 1.0122x over previous
//
#include <hip/hip_runtime.h>

#define NF 128
#define NBSHIFT 8        // 256 nodes per bucket
#define NBMAX 512        // padded bucket count for scans
#define CHUNK 4096       // edges per multisplit chunk
#define DCHUNK 4096      // nodes per degree-multisplit chunk

typedef __attribute__((ext_vector_type(8))) short bf16x8;
typedef __attribute__((ext_vector_type(4))) float f32x4;
typedef __attribute__((ext_vector_type(2))) float f32x2;

__device__ __forceinline__ unsigned short f2bf(float f) {
    unsigned int u = __builtin_bit_cast(unsigned int, f);
    u = (u + 0x7fffu + ((u >> 16) & 1u)) >> 16;
    return (unsigned short)u;
}
__device__ __forceinline__ float bflo(unsigned int u) {
    return __builtin_bit_cast(float, u << 16);
}
__device__ __forceinline__ float bfhi(unsigned int u) {
    return __builtin_bit_cast(float, u & 0xffff0000u);
}
__device__ __forceinline__ unsigned char f2fp8(float v) {
    return (unsigned char)(__builtin_amdgcn_cvt_pk_fp8_f32(v, v, 0, false) & 0xff);
}

// ================= tiny zero kernel =================
__global__ void k_zero(int* __restrict__ a, int na, int* __restrict__ b, int nb) {
    int i = blockIdx.x * blockDim.x + threadIdx.x;
    if (i < na) a[i] = 0;
    if (i < nb) b[i] = 0;
}

// ================= fused prep: bhist | buildBt | cvt(x -> bf16 + fp8) =================
#define BH 256
#define BT 256
__global__ __launch_bounds__(256) void k_prep(const int* __restrict__ dst, int E, int NB,
                                              int* __restrict__ gbhist,
                                              const float* __restrict__ x,
                                              unsigned short* __restrict__ xb,
                                              unsigned char* __restrict__ xq,
                                              const float* __restrict__ Win,
                                              const float* __restrict__ Wout,
                                              unsigned short* __restrict__ BtIn,
                                              unsigned short* __restrict__ BtOut) {
    __shared__ int lh[NBMAX];
    const int bb = blockIdx.x;
    const int t = threadIdx.x;
    if (bb < BH) {
        for (int k = t; k < NBMAX; k += 256) lh[k] = 0;
        __syncthreads();
        for (int i = bb * 256 + t; i < E; i += BH * 256)
            atomicAdd(&lh[((unsigned)dst[i]) >> NBSHIFT], 1);
        __syncthreads();
        for (int k = t; k < NB; k += 256)
            if (lh[k]) atomicAdd(&gbhist[k], lh[k]);
    } else if (bb < BH + BT) {
        int b2 = bb - BH;
        const float* W = (b2 < 128) ? Win : Wout;
        unsigned short* Bt = (b2 < 128) ? BtIn : BtOut;
        int idx = (b2 & 127) * 256 + t;
        int c = idx >> 8;
        int k = idx & 255;
        int p = k >> 7, kk = k & 127;
        Bt[idx] = f2bf(W[((size_t)p * NF + kk) * NF + c]);
    } else {
        long long i = (long long)(bb - BH - BT) * 256 + t;
        const float4 a = *reinterpret_cast<const float4*>(x + i * 8);
        const float4 b = *reinterpret_cast<const float4*>(x + i * 8 + 4);
        union { unsigned short s[8]; uint4 u; } o;
        o.s[0] = f2bf(a.x); o.s[1] = f2bf(a.y); o.s[2] = f2bf(a.z); o.s[3] = f2bf(a.w);
        o.s[4] = f2bf(b.x); o.s[5] = f2bf(b.y); o.s[6] = f2bf(b.z); o.s[7] = f2bf(b.w);
        *reinterpret_cast<uint4*>(xb + i * 8) = o.u;
        int lo = __builtin_amdgcn_cvt_pk_fp8_f32(a.x, a.y, 0, false);
        lo = __builtin_amdgcn_cvt_pk_fp8_f32(a.z, a.w, lo, true);
        int hi = __builtin_amdgcn_cvt_pk_fp8_f32(b.x, b.y, 0, false);
        hi = __builtin_amdgcn_cvt_pk_fp8_f32(b.z, b.w, hi, true);
        uint2 oq; oq.x = (unsigned)lo; oq.y = (unsigned)hi;
        *reinterpret_cast<uint2*>(xq + i * 8) = oq;
    }
}

// ================= CSR build =================

__global__ __launch_bounds__(256) void k_bscan(const int* __restrict__ gbhist,
                                               int* __restrict__ bbase, int* __restrict__ gcursor,
                                               int NB, int E, int* __restrict__ offsets, int n) {
    __shared__ int sA[NBMAX], sB[NBMAX];
    int t = threadIdx.x;
    for (int k = t; k < NBMAX; k += 256) sA[k] = (k < NB) ? gbhist[k] : 0;
    __syncthreads();
    int* pin = sA;
    int* pout = sB;
    for (int off = 1; off < NBMAX; off <<= 1) {
        for (int k = t; k < NBMAX; k += 256) pout[k] = pin[k] + (k >= off ? pin[k - off] : 0);
        __syncthreads();
        int* tmp = pin; pin = pout; pout = tmp;
    }
    for (int k = t; k < NB; k += 256) {
        int excl = pin[k] - gbhist[k];
        bbase[k] = excl;
        gcursor[k] = excl;
    }
    if (t == 0) {
        bbase[NB] = E;
        offsets[n] = E;
    }
}

// chunked multisplit; edge packed 32-bit: (dst&255)<<24 | src  (needs n < 2^24)
__global__ __launch_bounds__(256) void k_bucket(const int* __restrict__ src,
                                                const int* __restrict__ dst,
                                                int* __restrict__ gcursor,
                                                unsigned* __restrict__ gpairs, int E) {
    __shared__ int lhist[NBMAX], lbase[NBMAX], lcur[NBMAX], gb[NBMAX];
    __shared__ int sA[NBMAX], sB[NBMAX];
    __shared__ unsigned stage[CHUNK];
    __shared__ unsigned short stage_b[CHUNK];
    const int t = threadIdx.x;
    const int c0 = blockIdx.x * CHUNK;
    const int cc = min(CHUNK, E - c0);

    for (int k = t; k < NBMAX; k += 256) lhist[k] = 0;
    __syncthreads();

    int ls[16], ld[16];
#pragma unroll
    for (int j = 0; j < 16; ++j) {
        int i = t + j * 256;
        ls[j] = 0; ld[j] = 0;
        if (i < cc) {
            ls[j] = src[c0 + i];
            ld[j] = dst[c0 + i];
            atomicAdd(&lhist[((unsigned)ld[j]) >> NBSHIFT], 1);
        }
    }
    __syncthreads();
    for (int k = t; k < NBMAX; k += 256) sA[k] = lhist[k];
    __syncthreads();
    int* pin = sA;
    int* pout = sB;
    for (int off = 1; off < NBMAX; off <<= 1) {
        for (int k = t; k < NBMAX; k += 256) pout[k] = pin[k] + (k >= off ? pin[k - off] : 0);
        __syncthreads();
        int* tmp = pin; pin = pout; pout = tmp;
    }
    for (int k = t; k < NBMAX; k += 256) {
        int excl = pin[k] - lhist[k];
        lbase[k] = excl;
        lcur[k] = excl;
        int cnt = lhist[k];
        if (cnt > 0) gb[k] = atomicAdd(&gcursor[k], cnt);
    }
    __syncthreads();
#pragma unroll
    for (int j = 0; j < 16; ++j) {
        int i = t + j * 256;
        if (i < cc) {
            int b = ((unsigned)ld[j]) >> NBSHIFT;
            int pos = atomicAdd(&lcur[b], 1);
            stage[pos] = (((unsigned)ld[j] & 255u) << 24) | (unsigned)ls[j];
            stage_b[pos] = (unsigned short)b;
        }
    }
    __syncthreads();
    for (int idx = t; idx < cc; idx += 256) {
        unsigned p = stage[idx];
        int b = stage_b[idx];
        gpairs[gb[b] + (idx - lbase[b])] = p;
    }
}

// per-bucket: per-node hist + scan -> offsets/invdeg/degb, LDS-privatized global
// degree histogram, scatter esrc in bucket
__global__ __launch_bounds__(256) void k_bsort(const unsigned* __restrict__ gpairs,
                                               const int* __restrict__ bbase,
                                               int* __restrict__ offsets,
                                               float* __restrict__ invdeg,
                                               unsigned char* __restrict__ degb,
                                               int* __restrict__ gdhist,
                                               int* __restrict__ esrc, int n) {
    __shared__ int lcnt[256], lcur[256], sA[256], sB[256], ldh[256];
    const int b = blockIdx.x;
    const int t = threadIdx.x;
    const int base = bbase[b];
    const int c = bbase[b + 1] - base;
    const int n0 = b << NBSHIFT;

    lcnt[t] = 0;
    ldh[t] = 0;
    __syncthreads();
    for (int i = t; i < c; i += 256) {
        int node = (int)(gpairs[base + i] >> 24);
        atomicAdd(&lcnt[node], 1);
    }
    __syncthreads();
    sA[t] = lcnt[t];
    __syncthreads();
    int* pin = sA;
    int* pout = sB;
    for (int off = 1; off < 256; off <<= 1) {
        pout[t] = pin[t] + (t >= off ? pin[t - off] : 0);
        __syncthreads();
        int* tmp = pin; pin = pout; pout = tmp;
    }
    int excl = pin[t] - lcnt[t];
    lcur[t] = excl;
    int node_g = n0 + t;
    if (node_g < n) {
        offsets[node_g] = base + excl;
        invdeg[node_g] = 1.0f / (float)max(lcnt[t], 1);
        int d = min(lcnt[t], 255);
        degb[node_g] = (unsigned char)d;
        atomicAdd(&ldh[d], 1);   // LDS-privatized degree histogram
    }
    __syncthreads();
    if (ldh[t] > 0) atomicAdd(&gdhist[t], ldh[t]);  // <=256 global atomics/block
    for (int i = t; i < c; i += 256) {
        unsigned p = gpairs[base + i];
        int node = (int)(p >> 24);
        int pos = atomicAdd(&lcur[node], 1);
        esrc[base + pos] = (int)(p & 0x00ffffffu);
    }
}

// degree counting-sort pass 1: scan 256-bin hist -> global cursors (exclusive bases)
__global__ void k_dscan(const int* __restrict__ gdhist, int* __restrict__ dcur) {
    __shared__ int sh[256];
    int t = threadIdx.x;
    int v = gdhist[t];
    sh[t] = v;
    __syncthreads();
    for (int off = 1; off < 256; off <<= 1) {
        int x = (t >= off) ? sh[t - off] : 0;
        __syncthreads();
        sh[t] += x;
        __syncthreads();
    }
    dcur[t] = sh[t] - v;  // exclusive base
}

// degree counting-sort pass 2: chunked multisplit (one cursor atomic per bin per block)
__global__ __launch_bounds__(256) void k_dorder(const unsigned char* __restrict__ degb,
                                                int* __restrict__ dcur,
                                                int* __restrict__ dorder, int n) {
    __shared__ int lhist[256], lbase[256], lcur[256], gb[256], sA[256], sB[256];
    __shared__ int stageN[DCHUNK];
    __shared__ unsigned char stageD[DCHUNK];
    const int t = threadIdx.x;
    const int c0 = blockIdx.x * DCHUNK;
    const int cc = min(DCHUNK, n - c0);

    lhist[t] = 0;
    __syncthreads();
    int dloc[16];
#pragma unroll
    for (int j = 0; j < 16; ++j) {
        int i = t + j * 256;
        dloc[j] = -1;
        if (i < cc) {
            dloc[j] = degb[c0 + i];
            atomicAdd(&lhist[dloc[j]], 1);
        }
    }
    __syncthreads();
    sA[t] = lhist[t];
    __syncthreads();
    int* pin = sA;
    int* pout = sB;
    for (int off = 1; off < 256; off <<= 1) {
        pout[t] = pin[t] + (t >= off ? pin[t - off] : 0);
        __syncthreads();
        int* tmp = pin; pin = pout; pout = tmp;
    }
    int excl = pin[t] - lhist[t];
    lbase[t] = excl;
    lcur[t] = excl;
    if (lhist[t] > 0) gb[t] = atomicAdd(&dcur[t], lhist[t]);
    __syncthreads();
#pragma unroll
    for (int j = 0; j < 16; ++j) {
        int i = t + j * 256;
        if (i < cc) {
            int d = dloc[j];
            int pos = atomicAdd(&lcur[d], 1);
            stageN[pos] = c0 + i;
            stageD[pos] = (unsigned char)d;
        }
    }
    __syncthreads();
    for (int idx = t; idx < cc; idx += 256) {
        int d = stageD[idx];
        dorder[gb[d] + (idx - lbase[d])] = stageN[idx];
    }
}

// ================= gather aggregation: 8 nodes per wave, fp8 source, uint4 loads ======
// lane = (g = lane>>3: node slot, q = lane&7: 16B col group). One load instruction
// fetches 8 full 128B rows (1KB/wave); unroll-4 keeps 4KB in flight. No cross-lane
// data reduction -- each 8-lane group's partials ARE its node's 16 output columns.
// Nodes taken in degree-sorted order so the 8 slots run near-lockstep.
__global__ __launch_bounds__(256) void k_agg8(const unsigned char* __restrict__ feat,
                                              const int* __restrict__ esrc,
                                              const int* __restrict__ offsets,
                                              const float* __restrict__ invdeg,
                                              const int* __restrict__ dorder,
                                              unsigned short* __restrict__ neigh, int n) {
    const int tid = threadIdx.x;
    const int wv = (int)(((long long)blockIdx.x * blockDim.x + tid) >> 6);
    if (wv * 8 >= n) return;
    const int lane = tid & 63;
    const int g = lane >> 3;   // node slot 0..7
    const int q = lane & 7;    // 16B col group 0..7
    const int i8 = wv * 8 + g;

    int node = 0, beg = 0, deg = 0;
    if (i8 < n) {
        node = dorder[i8];
        beg = offsets[node];
        deg = offsets[node + 1] - beg;
    }
    int mn = deg, mx = deg;
    int s;
    s = __shfl_xor(mn, 8);  mn = min(mn, s);
    s = __shfl_xor(mx, 8);  mx = max(mx, s);
    s = __shfl_xor(mn, 16); mn = min(mn, s);
    s = __shfl_xor(mx, 16); mx = max(mx, s);
    s = __shfl_xor(mn, 32); mn = min(mn, s);
    s = __shfl_xor(mx, 32); mx = max(mx, s);
    const int mindeg = __builtin_amdgcn_readfirstlane(mn);
    const int maxdeg = __builtin_amdgcn_readfirstlane(mx);

    const unsigned qoff = (unsigned)q * 16u;
    f32x2 acc[8];
#pragma unroll
    for (int j = 0; j < 8; ++j) acc[j] = (f32x2){0.f, 0.f};

    int i = 0;
    for (; i + 4 <= mindeg; i += 4) {
        int e0 = esrc[beg + i + 0];
        int e1 = esrc[beg + i + 1];
        int e2 = esrc[beg + i + 2];
        int e3 = esrc[beg + i + 3];
        uint4 v0 = *(const uint4*)(feat + (unsigned)e0 * 128u + qoff);
        uint4 v1 = *(const uint4*)(feat + (unsigned)e1 * 128u + qoff);
        uint4 v2 = *(const uint4*)(feat + (unsigned)e2 * 128u + qoff);
        uint4 v3 = *(const uint4*)(feat + (unsigned)e3 * 128u + qoff);
#define ACC8(v)                                                       \
        acc[0] += __builtin_amdgcn_cvt_pk_f32_fp8((int)(v).x, false); \
        acc[1] += __builtin_amdgcn_cvt_pk_f32_fp8((int)(v).x, true);  \
        acc[2] += __builtin_amdgcn_cvt_pk_f32_fp8((int)(v).y, false); \
        acc[3] += __builtin_amdgcn_cvt_pk_f32_fp8((int)(v).y, true);  \
        acc[4] += __builtin_amdgcn_cvt_pk_f32_fp8((int)(v).z, false); \
        acc[5] += __builtin_amdgcn_cvt_pk_f32_fp8((int)(v).z, true);  \
        acc[6] += __builtin_amdgcn_cvt_pk_f32_fp8((int)(v).w, false); \
        acc[7] += __builtin_amdgcn_cvt_pk_f32_fp8((int)(v).w, true);
        ACC8(v0) ACC8(v1) ACC8(v2) ACC8(v3)
    }
    for (; i < maxdeg; ++i) {
        if (i < deg) {
            int e = esrc[beg + i];
            uint4 v = *(const uint4*)(feat + (unsigned)e * 128u + qoff);
            ACC8(v)
        }
    }
#undef ACC8

    if (i8 < n) {
        const float sc = invdeg[node];
        unsigned p[8];
#pragma unroll
        for (int j = 0; j < 8; ++j) {
            float ca = acc[j].x * sc, cb = acc[j].y * sc;
            asm("v_cvt_pk_bf16_f32 %0, %1, %2" : "=v"(p[j]) : "v"(ca), "v"(cb));
        }
        char* outb = (char*)neigh + (size_t)node * 256 + (unsigned)q * 32u;
        uint4 o0; o0.x = p[0]; o0.y = p[1]; o0.z = p[2]; o0.w = p[3];
        uint4 o1; o1.x = p[4]; o1.y = p[5]; o1.z = p[6]; o1.w = p[7];
        *(uint4*)outb = o0;
        *(uint4*)(outb + 16) = o1;
    }
}

// fallback bf16-source aggregate (non-fp8 path)
__global__ __launch_bounds__(256) void k_agg_bf16(const unsigned short* __restrict__ feat,
                                                  const int* __restrict__ esrc,
                                                  const int* __restrict__ offsets,
                                                  const float* __restrict__ invdeg,
                                                  unsigned short* __restrict__ neigh, int n) {
    int wid0 = (int)(((long long)blockIdx.x * blockDim.x + threadIdx.x) >> 6);
    const int wid = __builtin_amdgcn_readfirstlane(wid0);
    if (wid >= n) return;
    const int lane = threadIdx.x & 63;
    const int g = lane >> 4;
    const int q = lane & 15;
    const unsigned qoff = (unsigned)q * 16u;
    const char* fb = (const char*)feat;
    const int beg = offsets[wid];
    const int end = offsets[wid + 1];
    float a0 = 0.f, a1 = 0.f, a2 = 0.f, a3 = 0.f, a4 = 0.f, a5 = 0.f, a6 = 0.f, a7 = 0.f;
    int i = beg;
    for (; i + 4 <= end; i += 4) {
        int e0 = esrc[i + 0], e1 = esrc[i + 1], e2 = esrc[i + 2], e3 = esrc[i + 3];
        int es = (g & 2) ? ((g & 1) ? e3 : e2) : ((g & 1) ? e1 : e0);
        uint4 v = *(const uint4*)(fb + (unsigned)es * 256u + qoff);
        a0 += bflo(v.x); a1 += bfhi(v.x);
        a2 += bflo(v.y); a3 += bfhi(v.y);
        a4 += bflo(v.z); a5 += bfhi(v.z);
        a6 += bflo(v.w); a7 += bfhi(v.w);
    }
    if (i < end) {
        int r = end - i;
        if (g < r) {
            int es = esrc[i + g];
            uint4 v = *(const uint4*)(fb + (unsigned)es * 256u + qoff);
            a0 += bflo(v.x); a1 += bfhi(v.x);
            a2 += bflo(v.y); a3 += bfhi(v.y);
            a4 += bflo(v.z); a5 += bfhi(v.z);
            a6 += bflo(v.w); a7 += bfhi(v.w);
        }
    }
    a0 += __shfl_xor(a0, 16); a1 += __shfl_xor(a1, 16);
    a2 += __shfl_xor(a2, 16); a3 += __shfl_xor(a3, 16);
    a4 += __shfl_xor(a4, 16); a5 += __shfl_xor(a5, 16);
    a6 += __shfl_xor(a6, 16); a7 += __shfl_xor(a7, 16);
    a0 += __shfl_xor(a0, 32); a1 += __shfl_xor(a1, 32);
    a2 += __shfl_xor(a2, 32); a3 += __shfl_xor(a3, 32);
    a4 += __shfl_xor(a4, 32); a5 += __shfl_xor(a5, 32);
    a6 += __shfl_xor(a6, 32); a7 += __shfl_xor(a7, 32);
    const float sc = invdeg[wid];
    a0 *= sc; a1 *= sc; a2 *= sc; a3 *= sc;
    a4 *= sc; a5 *= sc; a6 *= sc; a7 *= sc;
    unsigned p0, p1, p2, p3;
    asm("v_cvt_pk_bf16_f32 %0, %1, %2" : "=v"(p0) : "v"(a0), "v"(a1));
    asm("v_cvt_pk_bf16_f32 %0, %1, %2" : "=v"(p1) : "v"(a2), "v"(a3));
    asm("v_cvt_pk_bf16_f32 %0, %1, %2" : "=v"(p2) : "v"(a4), "v"(a5));
    asm("v_cvt_pk_bf16_f32 %0, %1, %2" : "=v"(p3) : "v"(a6), "v"(a7));
    if (g == 0) {
        uint4 o; o.x = p0; o.y = p1; o.z = p2; o.w = p3;
        *(uint4*)((char*)neigh + (size_t)wid * 256 + qoff) = o;
    }
}

// fallback fp32-source aggregate
__global__ __launch_bounds__(256) void k_agg_f32(const float* __restrict__ feat,
                                                 const int* __restrict__ esrc,
                                                 const int* __restrict__ offsets,
                                                 const float* __restrict__ invdeg,
                                                 unsigned short* __restrict__ neigh, int n) {
    int wid0 = (int)(((long long)blockIdx.x * blockDim.x + threadIdx.x) >> 6);
    const int wid = __builtin_amdgcn_readfirstlane(wid0);
    if (wid >= n) return;
    int lane = threadIdx.x & 63;
    int beg = offsets[wid], end = offsets[wid + 1];
    float a0 = 0.f, a1 = 0.f;
    for (int i = beg; i < end; ++i) {
        int s0 = esrc[i];
        float2 v0 = *(const float2*)(feat + (size_t)s0 * NF + lane * 2);
        a0 += v0.x; a1 += v0.y;
    }
    float sc = invdeg[wid];
    unsigned pk;
    float ca = a0 * sc, cb = a1 * sc;
    asm("v_cvt_pk_bf16_f32 %0, %1, %2" : "=v"(pk) : "v"(ca), "v"(cb));
    *(unsigned*)(neigh + (size_t)wid * NF + lane * 2) = pk;
}

// ================= MFMA GEMM, LDS-staged (fp8 path) =================
template <bool RELU, bool OUTBF16, bool WRITEQ>
__global__ __launch_bounds__(256) void k_gemm_lds(const unsigned short* __restrict__ A1,
                                                  const unsigned short* __restrict__ A2,
                                                  const unsigned short* __restrict__ Bt,
                                                  void* __restrict__ outv,
                                                  unsigned char* __restrict__ outq,
                                                  int nrows) {
    __shared__ __align__(16) unsigned char sm[32768];  // [2][64 rows][128 k] bf16
    const int tid = threadIdx.x;
    const int w = tid >> 6;
    const int lane = tid & 63;
    const int l15 = lane & 15;
    const int lk = lane >> 4;  // 0..3
    const int col0 = w * 32;
    const int rbase = blockIdx.x * 64;

#pragma unroll
    for (int h = 0; h < 2; ++h) {
        const unsigned short* Ah = h ? A2 : A1;
#pragma unroll
        for (int j = 0; j < 4; ++j) {
            const int r = w * 16 + j * 4 + lk;
            const int garow = min(rbase + r, nrows - 1);
            const int cch = l15 ^ (r & 7);
            const unsigned short* srcp = Ah + (size_t)garow * NF + cch * 8;
            unsigned char* ldst = &sm[h * 16384 + (w * 16 + j * 4) * 256];
            __builtin_amdgcn_global_load_lds(
                (const __attribute__((address_space(1))) void*)srcp,
                (__attribute__((address_space(3))) void*)ldst, 16, 0, 0);
        }
    }

    bf16x8 breg[2][8];
#pragma unroll
    for (int c = 0; c < 2; ++c)
#pragma unroll
        for (int kc = 0; kc < 8; ++kc)
            breg[c][kc] = *(const bf16x8*)(Bt + (size_t)(col0 + c * 16 + l15) * 256 +
                                           kc * 32 + lk * 8);

    f32x4 acc[4][2];
#pragma unroll
    for (int rc = 0; rc < 4; ++rc) {
        acc[rc][0] = (f32x4)0.0f;
        acc[rc][1] = (f32x4)0.0f;
    }

    __syncthreads();

#pragma unroll
    for (int rc = 0; rc < 4; ++rc) {
        const int row = rc * 16 + l15;
#pragma unroll
        for (int kc = 0; kc < 8; ++kc) {
            const int half = kc >> 2;
            const int kk = kc & 3;
            const int chunk = (kk * 4 + lk) ^ (row & 7);
            const bf16x8 a = *(const bf16x8*)&sm[half * 16384 + row * 256 + chunk * 16];
            acc[rc][0] = __builtin_amdgcn_mfma_f32_16x16x32_bf16(a, breg[0][kc],
                                                                 acc[rc][0], 0, 0, 0);
            acc[rc][1] = __builtin_amdgcn_mfma_f32_16x16x32_bf16(a, breg[1][kc],
                                                                 acc[rc][1], 0, 0, 0);
        }
    }

    __syncthreads();

    if (OUTBF16) {
        unsigned short* smb = (unsigned short*)sm;
        unsigned char* smq = sm + 16384;
#pragma unroll
        for (int rc = 0; rc < 4; ++rc)
#pragma unroll
            for (int r = 0; r < 4; ++r) {
                const int row = rc * 16 + lk * 4 + r;
#pragma unroll
                for (int c = 0; c < 2; ++c) {
                    float v = acc[rc][c][r];
                    if (RELU) v = fmaxf(v, 0.f);
                    const int col = col0 + c * 16 + l15;
                    smb[row * NF + col] = f2bf(v);
                    if (WRITEQ) smq[row * NF + col] = f2fp8(v);
                }
            }
        __syncthreads();
#pragma unroll
        for (int it = 0; it < 4; ++it) {
            const int off = (tid + it * 256) * 16;
            if (rbase + (off >> 8) < nrows)
                *(uint4*)((char*)outv + (size_t)rbase * 256 + off) =
                    *(const uint4*)&sm[off];
        }
        if (WRITEQ) {
#pragma unroll
            for (int it = 0; it < 2; ++it) {
                const int off = (tid + it * 256) * 16;
                if (rbase + (off >> 7) < nrows)
                    *(uint4*)(outq + (size_t)rbase * 128 + off) =
                        *(const uint4*)&sm[16384 + off];
            }
        }
    } else {
        float* smf = (float*)sm;
#pragma unroll
        for (int rc = 0; rc < 4; ++rc)
#pragma unroll
            for (int r = 0; r < 4; ++r) {
                const int row = rc * 16 + lk * 4 + r;
#pragma unroll
                for (int c = 0; c < 2; ++c) {
                    float v = acc[rc][c][r];
                    if (RELU) v = fmaxf(v, 0.f);
                    smf[row * NF + col0 + c * 16 + l15] = v;
                }
            }
        __syncthreads();
#pragma unroll
        for (int it = 0; it < 8; ++it) {
            const int off = (tid + it * 256) * 16;
            if (rbase + (off >> 9) < nrows)
                *(uint4*)((char*)outv + (size_t)rbase * 512 + off) =
                    *(const uint4*)&sm[off];
        }
    }
}

// ================= fallback GEMM (non-fp8 path) =================
template <bool RELU, bool A1BF16, bool OUTBF16>
__global__ __launch_bounds__(256) void k_gemm_mfma(const void* __restrict__ A1v,
                                                   const unsigned short* __restrict__ A2,
                                                   const unsigned short* __restrict__ Bt,
                                                   void* __restrict__ outv, int nrows) {
    const int tid = threadIdx.x;
    const int wave = tid >> 6;
    const int lane = tid & 63;
    const int l15 = lane & 15;
    const int lk = lane >> 4;
    const int col0 = wave * 32;
    const int rbase = blockIdx.x * 64;

    bf16x8 breg[2][8];
#pragma unroll
    for (int c = 0; c < 2; ++c)
#pragma unroll
        for (int kc = 0; kc < 8; ++kc)
            breg[c][kc] = *(const bf16x8*)(Bt + (size_t)(col0 + c * 16 + l15) * 256 +
                                           kc * 32 + lk * 8);

    f32x4 acc[4][2];
#pragma unroll
    for (int rc = 0; rc < 4; ++rc) {
        acc[rc][0] = (f32x4)0.0f;
        acc[rc][1] = (f32x4)0.0f;
    }

#pragma unroll
    for (int rc = 0; rc < 4; ++rc) {
        const int arow = rbase + rc * 16 + l15;
        const bool ok = arow < nrows;
        bf16x8 a[8];
        if (ok) {
            if (A1BF16) {
                const unsigned short* A1 = (const unsigned short*)A1v;
#pragma unroll
                for (int kc = 0; kc < 4; ++kc) {
                    a[kc] = *(const bf16x8*)(A1 + (size_t)arow * NF + kc * 32 + lk * 8);
                    a[kc + 4] = *(const bf16x8*)(A2 + (size_t)arow * NF + kc * 32 + lk * 8);
                }
            } else {
                const float* A1 = (const float*)A1v;
#pragma unroll
                for (int kc = 0; kc < 4; ++kc) {
                    const float* p = A1 + (size_t)arow * NF + kc * 32 + lk * 8;
                    float4 u = *(const float4*)p;
                    float4 v = *(const float4*)(p + 4);
                    a[kc][0] = (short)f2bf(u.x); a[kc][1] = (short)f2bf(u.y);
                    a[kc][2] = (short)f2bf(u.z); a[kc][3] = (short)f2bf(u.w);
                    a[kc][4] = (short)f2bf(v.x); a[kc][5] = (short)f2bf(v.y);
                    a[kc][6] = (short)f2bf(v.z); a[kc][7] = (short)f2bf(v.w);
                    a[kc + 4] = *(const bf16x8*)(A2 + (size_t)arow * NF + kc * 32 + lk * 8);
                }
            }
        } else {
#pragma unroll
            for (int kc = 0; kc < 8; ++kc) a[kc] = (bf16x8)(short)0;
        }
#pragma unroll
        for (int kc = 0; kc < 8; ++kc) {
            acc[rc][0] = __builtin_amdgcn_mfma_f32_16x16x32_bf16(a[kc], breg[0][kc],
                                                                 acc[rc][0], 0, 0, 0);
            acc[rc][1] = __builtin_amdgcn_mfma_f32_16x16x32_bf16(a[kc], breg[1][kc],
                                                                 acc[rc][1], 0, 0, 0);
        }
    }

#pragma unroll
    for (int rc = 0; rc < 4; ++rc) {
#pragma unroll
        for (int r = 0; r < 4; ++r) {
            const int orow = rbase + rc * 16 + lk * 4 + r;
            if (orow >= nrows) continue;
#pragma unroll
            for (int c = 0; c < 2; ++c) {
                float v = acc[rc][c][r];
                if (RELU) v = fmaxf(v, 0.f);
                const int col = col0 + c * 16 + l15;
                if (OUTBF16)
                    ((unsigned short*)outv)[(size_t)orow * NF + col] = f2bf(v);
                else
                    ((float*)outv)[(size_t)orow * NF + col] = v;
            }
        }
    }
}

extern "C" void kernel_launch(void* const* d_in, const int* in_sizes, int n_in,
                              void* d_out, int out_size, void* d_ws, size_t ws_size,
                              hipStream_t stream) {
    const float* x = (const float*)d_in[0];
    const float* W_in = (const float*)d_in[1];
    const float* W_out = (const float*)d_in[2];
    const int* src = (const int*)d_in[3];
    const int* dst = (const int*)d_in[4];

    const int n = in_sizes[0] / NF;  // 100000  (must stay < 2^24 for packed CSR)
    const int E = in_sizes[3];       // 1600000
    float* outp = (float*)d_out;

    const int NB = (n + 255) >> NBSHIFT;
    const int nchunks = (E + CHUNK - 1) / CHUNK;

    // workspace carve
    char* ws = (char*)d_ws;
    size_t off = 0;
    auto take = [&](size_t bytes) {
        void* p = ws + off;
        off = (off + bytes + 511) & ~(size_t)511;
        return p;
    };
    int* gbhist = (int*)take((size_t)NB * 4);
    int* bbase = (int*)take((size_t)(NB + 1) * 4);
    int* gcursor = (int*)take((size_t)NB * 4);
    int* offsets = (int*)take((size_t)(n + 1) * 4);
    float* invdeg = (float*)take((size_t)n * 4);
    unsigned short* BtIn = (unsigned short*)take(128 * 256 * 2);
    unsigned short* BtOut = (unsigned short*)take(128 * 256 * 2);
    unsigned* gpairs = (unsigned*)take((size_t)E * 4);
    int* esrc = (int*)take((size_t)E * 4);
    unsigned short* hb = (unsigned short*)take((size_t)n * NF * 2);
    unsigned short* neigh = (unsigned short*)take((size_t)n * NF * 2);
    unsigned char* degb = (unsigned char*)take((size_t)n);
    int* gdhist = (int*)take(256 * 4);
    int* dcur = (int*)take(256 * 4);
    int* dorder = (int*)take((size_t)n * 4);
    size_t need_fp8 = off + (size_t)n * NF * 2 + 512 + (size_t)n * NF + 512 +
                      (size_t)n * NF + 512;
    bool use_fp8 = (ws_size >= need_fp8);
    unsigned short* xb = nullptr;
    unsigned char* xq = nullptr;
    unsigned char* hq = nullptr;
    if (use_fp8) {
        xb = (unsigned short*)take((size_t)n * NF * 2);
        xq = (unsigned char*)take((size_t)n * NF);
        hq = (unsigned char*)take((size_t)n * NF);
    }
    bool use_xb = use_fp8 || (ws_size >= off + (size_t)n * NF * 2);
    if (!use_fp8 && use_xb) xb = (unsigned short*)take((size_t)n * NF * 2);

    // ---- zero counters (custom kernel; runtime fills are slow in-graph) ----
    k_zero<<<(max(NB, 256) + 255) / 256, 256, 0, stream>>>(gbhist, NB, gdhist, 256);

    // ---- fused prep (bhist | buildBt | x->bf16+fp8) + CSR build ----
    const int cvtBlocks = use_fp8 ? (int)(((long long)n * NF / 8 + 255) / 256) : 0;
    k_prep<<<BH + BT + cvtBlocks, 256, 0, stream>>>(dst, E, NB, gbhist, x, xb, xq,
                                                    W_in, W_out, BtIn, BtOut);
    k_bscan<<<1, 256, 0, stream>>>(gbhist, bbase, gcursor, NB, E, offsets, n);
    k_bucket<<<nchunks, 256, 0, stream>>>(src, dst, gcursor, gpairs, E);
    k_bsort<<<NB, 256, 0, stream>>>(gpairs, bbase, offsets, invdeg, degb, gdhist, esrc, n);

    const int gemmBlocks = (n + 63) / 64;

    if (use_fp8) {
        // degree counting-sort -> dorder (multisplit, low-contention)
        k_dscan<<<1, 256, 0, stream>>>(gdhist, dcur);
        k_dorder<<<(n + DCHUNK - 1) / DCHUNK, 256, 0, stream>>>(degb, dcur, dorder, n);

        const int agg8Blocks = (n + 31) / 32;  // 32 nodes per 256-thread block
        // ---- layer 0 ----
        k_agg8<<<agg8Blocks, 256, 0, stream>>>(xq, esrc, offsets, invdeg, dorder, neigh, n);
        k_gemm_lds<true, true, true>
            <<<gemmBlocks, 256, 0, stream>>>(xb, neigh, BtIn, hb, hq, n);
        // ---- layer 1 ----
        k_agg8<<<agg8Blocks, 256, 0, stream>>>(hq, esrc, offsets, invdeg, dorder, neigh, n);
        k_gemm_lds<false, false, false>
            <<<gemmBlocks, 256, 0, stream>>>(hb, neigh, BtOut, outp, nullptr, n);
    } else {
        const int aggBlocks = (n + 3) / 4;
        k_agg_f32<<<aggBlocks, 256, 0, stream>>>(x, esrc, offsets, invdeg, neigh, n);
        k_gemm_mfma<true, false, true>
            <<<gemmBlocks, 256, 0, stream>>>(x, neigh, BtIn, hb, n);
        k_agg_bf16<<<aggBlocks, 256, 0, stream>>>(hb, esrc, offsets, invdeg, neigh, n);
        k_gemm_mfma<false, true, false>
            <<<gemmBlocks, 256, 0, stream>>>(hb, neigh, BtOut, outp, n);
    }
}